// Round 14
// baseline (285.465 us; speedup 1.0000x reference)
//
#include <hip/hip_runtime.h>
#include <hip/hip_bf16.h>

#define TT 2048
#define BB 4
#define HH 8
#define KK 256
#define MM (BB*TT)      // 8192 tokens
#define NQKV 6144
#define QKS 4096        // packed Q|K row stride

typedef __attribute__((ext_vector_type(8))) short bf16x8;
typedef __attribute__((ext_vector_type(4))) float f32x4;

__device__ __forceinline__ void gld_lds16(const void* g, void* lds) {
    __builtin_amdgcn_global_load_lds(
        (const __attribute__((address_space(1))) unsigned int*)g,
        (__attribute__((address_space(3))) unsigned int*)lds, 16, 0, 0);
}

// ---------------- fused prep: x->bf16 + 6 weight transpose-converts ----------------
// blocks 0..2047: cvt; 2048..4607: transpose jobs (one 32x32 tile each).
__global__ __launch_bounds__(256) void prep_k(
    const float* __restrict__ x, __hip_bfloat16* __restrict__ xb,
    const float* __restrict__ wq, const float* __restrict__ wk,
    const float* __restrict__ wv, const float* __restrict__ wu,
    const float* __restrict__ w1, const float* __restrict__ w2,
    __hip_bfloat16* __restrict__ wqkvT, __hip_bfloat16* __restrict__ wuT,
    __hip_bfloat16* __restrict__ w1T, __hip_bfloat16* __restrict__ w2T) {
    __shared__ float tile[32][33];
    int bid = blockIdx.x, tid = threadIdx.x;
    if (bid < 2048) {
        int i = (bid * 256 + tid) * 4;
        float4 v = *(const float4*)(x + i);
        xb[i + 0] = __float2bfloat16(v.x);
        xb[i + 1] = __float2bfloat16(v.y);
        xb[i + 2] = __float2bfloat16(v.z);
        xb[i + 3] = __float2bfloat16(v.w);
        return;
    }
    int t = bid - 2048;
    const float* in; __hip_bfloat16* out; int R, C, cx, ry;
    if (t < 1536) {                         // wq / wk / wv: 256 x 2048, 512 blocks each
        int j = t >> 9, u = t & 511;
        in = (j == 0) ? wq : (j == 1 ? wk : wv);
        out = wqkvT + (size_t)j * 2048 * 256;
        R = 256; C = 2048; cx = u & 63; ry = u >> 6;
    } else if (t < 2048) {                  // wu: 2048 x 256
        int u = t - 1536; in = wu; out = wuT; R = 2048; C = 256; cx = u & 7; ry = u >> 3;
    } else if (t < 2304) {                  // w1: 256 x 1024
        int u = t - 2048; in = w1; out = w1T; R = 256; C = 1024; cx = u & 31; ry = u >> 5;
    } else {                                // w2: 1024 x 256
        int u = t - 2304; in = w2; out = w2T; R = 1024; C = 256; cx = u & 7; ry = u >> 3;
    }
    int c0 = cx * 32, r0 = ry * 32;
    int tx = tid & 31, ty = tid >> 5;
    #pragma unroll
    for (int i = ty; i < 32; i += 8)
        tile[i][tx] = in[(size_t)(r0 + i) * C + c0 + tx];
    __syncthreads();
    #pragma unroll
    for (int i = ty; i < 32; i += 8)
        out[(size_t)(c0 + i) * R + r0 + tx] = __float2bfloat16(tile[tx][i]);
}

// ---------------- GEMM, 2-phase pipelined, BK=64, packed-512B-row LDS ----------------
// EPI 0: QKV fused epilogue: col<4096 -> qk (stride 4096, *scale);
//        col>=4096 -> V transposed into vt (B*H, 256, T)
// EPI 1: fused LayerNorm epilogue (requires BN==N==256): v = acc+bias+res;
//        row mean/var via l15-butterfly + 2-slot LDS cross-wave combine;
//        writes out_f (f32) and optional outb (bf16)
// EPI 2: out bf16 = relu(acc + bias[col])
template<int EPI, int BN>
__global__ __launch_bounds__(256) void gemm_k(const __hip_bfloat16* __restrict__ A,
                                              const __hip_bfloat16* __restrict__ Bt,
                                              int M, int N, int Kd,
                                              const float* __restrict__ bias,
                                              const float* __restrict__ res,
                                              void* __restrict__ outp, float scale,
                                              __hip_bfloat16* __restrict__ vtp,
                                              const float* __restrict__ gamma,
                                              const float* __restrict__ beta,
                                              __hip_bfloat16* __restrict__ outb) {
    constexpr int NF = BN / 32;
    constexpr int BPHYS = BN / 4;            // physical 512-B rows in B tile
    constexpr int SWZM = (BPHYS - 1) & 31;   // XOR mask (granule index is 5 bits)
    __shared__ short sA[2][128 * 64];        // 16 KB per buffer
    __shared__ short sB[2][BN * 64];
    __shared__ float redS[EPI == 1 ? 128 : 1][2];
    __shared__ float redQ[EPI == 1 ? 128 : 1][2];
    int tid = threadIdx.x, lane = tid & 63, wave = tid >> 6;
    int l15 = lane & 15, g = lane >> 4;
    int m0 = blockIdx.y * 128, n0 = blockIdx.x * BN;
    int wm = (wave >> 1) * 64, wn = (wave & 1) * (BN / 2);
    f32x4 acc[4][NF] = {};
    const int NT = Kd >> 6;

    auto STAGE = [&](int kt, int buf) {
        #pragma unroll
        for (int c = 0; c < 4; ++c) {            // A: 128 rows x 128 B = 16 KB
            int L = c * 4096 + tid * 16;
            int phys = L >> 9;                   // 0..31
            int vp = ((L >> 4) & 31) ^ phys;     // unswizzled slot
            int row = (vp >> 3) * 32 + phys;
            gld_lds16(A + (size_t)(m0 + row) * Kd + kt * 64 + (vp & 7) * 8,
                      (char*)sA[buf] + L);
        }
        #pragma unroll
        for (int c = 0; c < BN / 32; ++c) {      // B: BN rows x 128 B
            int L = c * 4096 + tid * 16;
            int phys = L >> 9;                   // 0..BPHYS-1
            int vp = ((L >> 4) & 31) ^ (phys & SWZM);
            int row = (vp >> 3) * BPHYS + phys;
            gld_lds16(Bt + (size_t)(n0 + row) * Kd + kt * 64 + (vp & 7) * 8,
                      (char*)sB[buf] + L);
        }
    };

    STAGE(0, 0);
    asm volatile("s_waitcnt vmcnt(0)" ::: "memory");
    __syncthreads();
    int cur = 0;
    for (int kt = 0; kt < NT; ++kt) {
        if (kt + 1 < NT) STAGE(kt + 1, cur ^ 1);   // issue next tile early
        #pragma unroll
        for (int kk = 0; kk < 2; ++kk) {
            bf16x8 af[4], bfr[NF];
            #pragma unroll
            for (int mf = 0; mf < 4; ++mf) {
                int R = wm + mf * 16 + l15;
                int v = (((R >> 5) << 3) + (kk << 2) + g) ^ (R & 31);
                af[mf] = *(const bf16x8*)((char*)sA[cur] + ((R & 31) << 9) + (v << 4));
            }
            #pragma unroll
            for (int nf = 0; nf < NF; ++nf) {
                int R = wn + nf * 16 + l15;
                int v = ((R / BPHYS) * 8 + (kk << 2) + g) ^ (R & SWZM);
                bfr[nf] = *(const bf16x8*)((char*)sB[cur] + ((R % BPHYS) << 9) + (v << 4));
            }
            #pragma unroll
            for (int mf = 0; mf < 4; ++mf)
                #pragma unroll
                for (int nf = 0; nf < NF; ++nf)
                    acc[mf][nf] = __builtin_amdgcn_mfma_f32_16x16x32_bf16(af[mf], bfr[nf], acc[mf][nf], 0, 0, 0);
        }
        asm volatile("s_waitcnt vmcnt(0)" ::: "memory");   // next tile landed
        __syncthreads();                                    // all waves done with cur
        cur ^= 1;
    }

    if (EPI == 1) {
        // pass 1: v = acc + bias + res; per-row partial sums (this wave's 128-col half)
        #pragma unroll
        for (int mf = 0; mf < 4; ++mf) {
            #pragma unroll
            for (int r = 0; r < 4; ++r) {
                int lrow = wm + mf * 16 + g * 4 + r;
                int rowb = m0 + lrow;
                float s = 0.f, qq = 0.f;
                #pragma unroll
                for (int nf = 0; nf < NF; ++nf) {
                    int col = n0 + wn + nf * 16 + l15;
                    float v = acc[mf][nf][r] + bias[col] + res[(size_t)rowb * N + col];
                    acc[mf][nf][r] = v;
                    s += v; qq += v * v;
                }
                #pragma unroll
                for (int d = 1; d < 16; d <<= 1) { s += __shfl_xor(s, d); qq += __shfl_xor(qq, d); }
                if (l15 == 0) { redS[lrow][wave & 1] = s; redQ[lrow][wave & 1] = qq; }
            }
        }
        __syncthreads();
        // pass 2: combine halves, normalize, write
        #pragma unroll
        for (int mf = 0; mf < 4; ++mf) {
            #pragma unroll
            for (int r = 0; r < 4; ++r) {
                int lrow = wm + mf * 16 + g * 4 + r;
                int rowb = m0 + lrow;
                float s = redS[lrow][0] + redS[lrow][1];
                float qq = redQ[lrow][0] + redQ[lrow][1];
                float mu = s * (1.0f / 256.0f);
                float rs = rsqrtf(qq * (1.0f / 256.0f) - mu * mu + 1e-5f);
                #pragma unroll
                for (int nf = 0; nf < NF; ++nf) {
                    int col = n0 + wn + nf * 16 + l15;
                    size_t idx = (size_t)rowb * N + col;
                    float o = (acc[mf][nf][r] - mu) * rs * gamma[col] + beta[col];
                    ((float*)outp)[idx] = o;
                    if (outb) outb[idx] = __float2bfloat16(o);
                }
            }
        }
        return;
    }

    #pragma unroll
    for (int mf = 0; mf < 4; ++mf) {
        int rowb = m0 + wm + mf * 16 + g * 4;
        #pragma unroll
        for (int nf = 0; nf < NF; ++nf) {
            int col = n0 + wn + nf * 16 + l15;
            if (EPI == 0) {
                if (col < 4096) {
                    #pragma unroll
                    for (int r = 0; r < 4; ++r)
                        ((__hip_bfloat16*)outp)[(size_t)(rowb + r) * QKS + col] =
                            __float2bfloat16(acc[mf][nf][r] * scale);
                } else {
                    int hv = col - 4096, h = hv >> 8, d = hv & 255;
                    int b = rowb >> 11, t = rowb & 2047;
                    ushort4 w;
                    w.x = __bfloat16_as_ushort(__float2bfloat16(acc[mf][nf][0]));
                    w.y = __bfloat16_as_ushort(__float2bfloat16(acc[mf][nf][1]));
                    w.z = __bfloat16_as_ushort(__float2bfloat16(acc[mf][nf][2]));
                    w.w = __bfloat16_as_ushort(__float2bfloat16(acc[mf][nf][3]));
                    *(ushort4*)(vtp + ((size_t)((b * 8 + h) * 256 + d)) * TT + t) = w;
                }
            } else {
                #pragma unroll
                for (int r = 0; r < 4; ++r) {
                    float v = acc[mf][nf][r] + bias[col];
                    ((__hip_bfloat16*)outp)[(size_t)(rowb + r) * N + col] =
                        __float2bfloat16(v > 0.0f ? v : 0.0f);
                }
            }
        }
    }
}

// ---------------- flash attention: 8 waves x 16 q-rows, dbuf LDS, swapped-QK softmax ----
// (round-8 proven version, verbatim: 125 us, VGPR 116, no spill)
__global__ __launch_bounds__(512, 2) void attn_k(const __hip_bfloat16* __restrict__ QK,
                                                 const __hip_bfloat16* __restrict__ VT,
                                                 __hip_bfloat16* __restrict__ O) {
    __shared__ char Kl[2][32768];
    __shared__ char Vl[2][32768];
    __shared__ char Pl[8][2048];     // per-wave P: [16 q][64 s] bf16, XOR-swizzled
    int tid = threadIdx.x, lane = tid & 63, wave = tid >> 6;
    int id = blockIdx.x;
    int xcd = id & 7, w = id >> 3;            // w: 0..31
    int bh = xcd * 4 + (w >> 3);
    int jtp = w & 7;
    int b = bh >> 3, h = bh & 7;
    const __hip_bfloat16* Qb = QK + (size_t)b * TT * QKS + h * KK;
    const __hip_bfloat16* Kb = Qb + 2048;
    const __hip_bfloat16* Vtb = VT + (size_t)bh * KK * TT;

    int l15 = lane & 15, g = lane >> 4;
    int koff = g * 8;            // elements
    int koffB = g * 16;          // bytes
    int pswz = (l15 & 7) << 4;   // P-tile swizzle for this lane's q-row

    auto STAGE = [&](int s0, int buf) {
        #pragma unroll
        for (int rd = 0; rd < 4; ++rd) {        // K: 64 rows x 512 B
            int L = rd * 8192 + tid * 16;
            int row = L >> 9;
            int cb = (L & 511) ^ ((row & 7) << 4);
            gld_lds16((const char*)(Kb + (size_t)(s0 + row) * QKS) + cb,
                      Kl[buf] + rd * 8192 + wave * 1024);
        }
        #pragma unroll
        for (int rd = 0; rd < 4; ++rd) {        // V: 256 rows x 128 B
            int L = rd * 8192 + tid * 16;
            int row = L >> 7;
            int cb = (L & 127) ^ ((row & 7) << 4);
            gld_lds16((const char*)(Vtb + (size_t)row * TT + s0) + cb,
                      Vl[buf] + rd * 8192 + wave * 1024);
        }
    };

    #pragma unroll 1
    for (int half = 0; half < 2; ++half) {
        int jt = (half == 0) ? jtp : 15 - jtp;
        int q0 = jt * 128;
        int rowbase = q0 + wave * 16;
        bf16x8 qf[8];
        #pragma unroll
        for (int kk = 0; kk < 8; ++kk)
            qf[kk] = *(const bf16x8*)(Qb + (size_t)(rowbase + l15) * QKS + kk * 32 + koff);

        f32x4 Oa[16] = {};
        float mrow = -__builtin_inff();
        float lrow = 0.f;

        STAGE(0, 0);
        asm volatile("s_waitcnt vmcnt(0)" ::: "memory");
        __syncthreads();
        int cur = 0;
        const int niter = 2 * jt + 2;

        #pragma unroll 1
        for (int i = 0; i < niter; ++i) {
            int s0 = i * 64;
            if (i + 1 < niter) STAGE(s0 + 64, cur ^ 1);   // prefetch into other buffer

            if (s0 <= rowbase + 15) {                     // wave has unmasked rows
                // ---- QK^T swapped: S = K-tile x Q-frag (lane col = q = l15)
                f32x4 S[4] = {};
                __builtin_amdgcn_s_setprio(1);
                #pragma unroll
                for (int nf = 0; nf < 4; ++nf) {
                    int r = nf * 16 + l15;
                    int swz = (r & 7) << 4;
                    #pragma unroll
                    for (int kk = 0; kk < 8; ++kk) {
                        bf16x8 kf = *(const bf16x8*)(Kl[cur] + r * 512 + ((kk * 64 + koffB) ^ swz));
                        S[nf] = __builtin_amdgcn_mfma_f32_16x16x32_bf16(kf, qf[kk], S[nf], 0, 0, 0);
                    }
                }
                __builtin_amdgcn_s_setprio(0);
                if (s0 + 63 > rowbase) {                  // causal: S row = s, col = q
                    int qg = rowbase + l15;
                    #pragma unroll
                    for (int nf = 0; nf < 4; ++nf)
                        #pragma unroll
                        for (int r = 0; r < 4; ++r) {
                            int sg = s0 + nf * 16 + g * 4 + r;
                            if (sg > qg) S[nf][r] = -__builtin_inff();
                        }
                }
                // ---- softmax (exp2 domain), stats lane-local in l15
                float mx = S[0][0];
                #pragma unroll
                for (int nf = 0; nf < 4; ++nf)
                    #pragma unroll
                    for (int r = 0; r < 4; ++r) mx = fmaxf(mx, S[nf][r]);
                mx = fmaxf(mx, __shfl_xor(mx, 16));
                mx = fmaxf(mx, __shfl_xor(mx, 32));
                if (__any(mx > mrow + 8.0f)) {            // defer-max rescale
                    float mn = fmaxf(mrow, mx);
                    float alpha = exp2f(mrow - mn);
                    mrow = mn;
                    lrow *= alpha;
                    float al[4];
                    #pragma unroll
                    for (int r = 0; r < 4; ++r) al[r] = __shfl(alpha, (g << 2) + r);
                    #pragma unroll
                    for (int nf2 = 0; nf2 < 16; ++nf2)
                        #pragma unroll
                        for (int r = 0; r < 4; ++r) Oa[nf2][r] *= al[r];
                }
                float ps = 0.f;
                #pragma unroll
                for (int nf = 0; nf < 4; ++nf)
                    #pragma unroll
                    for (int r = 0; r < 4; ++r) {
                        float p = exp2f(S[nf][r] - mrow);
                        S[nf][r] = p; ps += p;
                    }
                ps += __shfl_xor(ps, 16);
                ps += __shfl_xor(ps, 32);
                lrow += ps;
                // ---- P -> LDS [q=l15][s], b64 packed writes, swizzled
                #pragma unroll
                for (int nf = 0; nf < 4; ++nf) {
                    uint2 pk2;
                    pk2.x = (unsigned)__bfloat16_as_ushort(__float2bfloat16(S[nf][0]))
                          | ((unsigned)__bfloat16_as_ushort(__float2bfloat16(S[nf][1])) << 16);
                    pk2.y = (unsigned)__bfloat16_as_ushort(__float2bfloat16(S[nf][2]))
                          | ((unsigned)__bfloat16_as_ushort(__float2bfloat16(S[nf][3])) << 16);
                    *(uint2*)(Pl[wave] + l15 * 128 + ((nf * 32 + g * 8) ^ pswz)) = pk2;
                }
                // ---- PV: O += P @ V
                bf16x8 pa[2];
                #pragma unroll
                for (int kk2 = 0; kk2 < 2; ++kk2)
                    pa[kk2] = *(const bf16x8*)(Pl[wave] + l15 * 128 + ((kk2 * 64 + koffB) ^ pswz));
                __builtin_amdgcn_s_setprio(1);
                #pragma unroll
                for (int nf2 = 0; nf2 < 16; ++nf2) {
                    int r = nf2 * 16 + l15;
                    int swz = (r & 7) << 4;
                    #pragma unroll
                    for (int kk2 = 0; kk2 < 2; ++kk2) {
                        bf16x8 vb = *(const bf16x8*)(Vl[cur] + r * 128 + ((kk2 * 64 + koffB) ^ swz));
                        Oa[nf2] = __builtin_amdgcn_mfma_f32_16x16x32_bf16(pa[kk2], vb, Oa[nf2], 0, 0, 0);
                    }
                }
                __builtin_amdgcn_s_setprio(0);
            }
            asm volatile("s_waitcnt vmcnt(0)" ::: "memory");   // own prefetch landed
            __syncthreads();                                    // all waves done + staged
            cur ^= 1;
        }
        // ---- write this q-tile's output
        float rcp_ = 1.0f / lrow;
        float rc[4];
        #pragma unroll
        for (int r = 0; r < 4; ++r) rc[r] = __shfl(rcp_, (g << 2) + r);
        #pragma unroll
        for (int nf2 = 0; nf2 < 16; ++nf2) {
            int col = nf2 * 16 + l15;
            #pragma unroll
            for (int r = 0; r < 4; ++r) {
                int t = rowbase + g * 4 + r;
                O[((size_t)b * TT + t) * 2048 + h * KK + col] = __float2bfloat16(Oa[nf2][r] * rc[r]);
            }
        }
    }
}

extern "C" void kernel_launch(void* const* d_in, const int* in_sizes, int n_in,
                              void* d_out, int out_size, void* d_ws, size_t ws_size,
                              hipStream_t stream) {
    const float* x  = (const float*)d_in[0];
    const float* wq = (const float*)d_in[1];
    const float* wk = (const float*)d_in[2];
    const float* wv = (const float*)d_in[3];
    const float* wu = (const float*)d_in[4];
    const float* bu = (const float*)d_in[5];
    const float* w1 = (const float*)d_in[6];
    const float* b1 = (const float*)d_in[7];
    const float* w2 = (const float*)d_in[8];
    const float* b2 = (const float*)d_in[9];
    const float* g1 = (const float*)d_in[10];
    const float* be1 = (const float*)d_in[11];
    const float* g2 = (const float*)d_in[12];
    const float* be2 = (const float*)d_in[13];

    char* p = (char*)d_ws;
    auto alloc = [&](size_t bytes) { char* r = p; p += bytes; return r; };
    __hip_bfloat16* xb    = (__hip_bfloat16*)alloc((size_t)MM * KK * 2);
    __hip_bfloat16* wqkvT = (__hip_bfloat16*)alloc((size_t)NQKV * KK * 2);
    __hip_bfloat16* wuT   = (__hip_bfloat16*)alloc((size_t)KK * 2048 * 2);
    __hip_bfloat16* w1T   = (__hip_bfloat16*)alloc((size_t)1024 * KK * 2);
    __hip_bfloat16* w2T   = (__hip_bfloat16*)alloc((size_t)KK * 1024 * 2);
    __hip_bfloat16* qk    = (__hip_bfloat16*)alloc((size_t)MM * QKS * 2);
    __hip_bfloat16* vt    = (__hip_bfloat16*)alloc((size_t)32 * KK * TT * 2);
    __hip_bfloat16* attn  = (__hip_bfloat16*)alloc((size_t)MM * 2048 * 2);
    float*          x1    = (float*)alloc((size_t)MM * KK * 4);
    __hip_bfloat16* x1b   = (__hip_bfloat16*)alloc((size_t)MM * KK * 2);
    __hip_bfloat16* hid   = (__hip_bfloat16*)alloc((size_t)MM * 1024 * 2);

    // 1. fused prep (cvt + 6 transposes)
    prep_k<<<4608, 256, 0, stream>>>(x, xb, wq, wk, wv, wu, w1, w2,
                                     wqkvT, wuT, w1T, w2T);

    // 2. QKV projection; q/k scale 0.25*sqrt(log2 e); V fused-transposed into vt
    gemm_k<0, 128><<<dim3(NQKV / 128, MM / 128), 256, 0, stream>>>(
        xb, wqkvT, MM, NQKV, 256, nullptr, nullptr, qk, 0.3002806f, vt,
        nullptr, nullptr, nullptr);

    // 3. flash attention
    attn_k<<<dim3(256), 512, 0, stream>>>(qk, vt, attn);

    // 4. attn-out proj + residual + LN1 (fused epilogue) -> x1 (f32) + x1b (bf16)
    gemm_k<1, 256><<<dim3(1, MM / 128), 256, 0, stream>>>(
        attn, wuT, MM, 256, 2048, bu, x, x1, 1.0f, nullptr, g1, be1, x1b);

    // 5. FFN1: relu(x1b @ w1 + b1) -> hid (bf16)
    gemm_k<2, 128><<<dim3(8, MM / 128), 256, 0, stream>>>(
        x1b, w1T, MM, 1024, 256, b1, nullptr, hid, 1.0f, nullptr,
        nullptr, nullptr, nullptr);

    // 6. FFN2 + residual + LN2 (fused epilogue) -> d_out (f32)
    gemm_k<1, 256><<<dim3(1, MM / 128), 256, 0, stream>>>(
        hid, w2T, MM, 256, 1024, b2, x1, (float*)d_out, 1.0f, nullptr, g2, be2, nullptr);
}

// Round 15
// 252.713 us; speedup vs baseline: 1.1296x; 1.1296x over previous
//
#include <hip/hip_runtime.h>
#include <hip/hip_bf16.h>

#define TT 2048
#define BB 4
#define HH 8
#define KK 256
#define MM (BB*TT)      // 8192 tokens
#define NQKV 6144
#define QKS 4096        // packed Q|K row stride

typedef __attribute__((ext_vector_type(8))) short bf16x8;
typedef __attribute__((ext_vector_type(4))) float f32x4;

__device__ __forceinline__ void gld_lds16(const void* g, void* lds) {
    __builtin_amdgcn_global_load_lds(
        (const __attribute__((address_space(1))) unsigned int*)g,
        (__attribute__((address_space(3))) unsigned int*)lds, 16, 0, 0);
}

// ---------------- fused prep: x->bf16 + 6 weight transpose-converts ----------------
__global__ __launch_bounds__(256) void prep_k(
    const float* __restrict__ x, __hip_bfloat16* __restrict__ xb,
    const float* __restrict__ wq, const float* __restrict__ wk,
    const float* __restrict__ wv, const float* __restrict__ wu,
    const float* __restrict__ w1, const float* __restrict__ w2,
    __hip_bfloat16* __restrict__ wqkvT, __hip_bfloat16* __restrict__ wuT,
    __hip_bfloat16* __restrict__ w1T, __hip_bfloat16* __restrict__ w2T) {
    __shared__ float tile[32][33];
    int bid = blockIdx.x, tid = threadIdx.x;
    if (bid < 2048) {
        int i = (bid * 256 + tid) * 4;
        float4 v = *(const float4*)(x + i);
        xb[i + 0] = __float2bfloat16(v.x);
        xb[i + 1] = __float2bfloat16(v.y);
        xb[i + 2] = __float2bfloat16(v.z);
        xb[i + 3] = __float2bfloat16(v.w);
        return;
    }
    int t = bid - 2048;
    const float* in; __hip_bfloat16* out; int R, C, cx, ry;
    if (t < 1536) {                         // wq / wk / wv: 256 x 2048
        int j = t >> 9, u = t & 511;
        in = (j == 0) ? wq : (j == 1 ? wk : wv);
        out = wqkvT + (size_t)j * 2048 * 256;
        R = 256; C = 2048; cx = u & 63; ry = u >> 6;
    } else if (t < 2048) {                  // wu: 2048 x 256
        int u = t - 1536; in = wu; out = wuT; R = 2048; C = 256; cx = u & 7; ry = u >> 3;
    } else if (t < 2304) {                  // w1: 256 x 1024
        int u = t - 2048; in = w1; out = w1T; R = 256; C = 1024; cx = u & 31; ry = u >> 5;
    } else {                                // w2: 1024 x 256
        int u = t - 2304; in = w2; out = w2T; R = 1024; C = 256; cx = u & 7; ry = u >> 3;
    }
    int c0 = cx * 32, r0 = ry * 32;
    int tx = tid & 31, ty = tid >> 5;
    #pragma unroll
    for (int i = ty; i < 32; i += 8)
        tile[i][tx] = in[(size_t)(r0 + i) * C + c0 + tx];
    __syncthreads();
    #pragma unroll
    for (int i = ty; i < 32; i += 8)
        out[(size_t)(c0 + i) * R + r0 + tx] = __float2bfloat16(tile[tx][i]);
}

// ---------------- GEMM, 2-phase pipelined, BK=64, packed-512B-row LDS ----------------
// EPI 0: QKV fused epilogue: col<4096 -> qk (stride 4096, *scale);
//        col>=4096 -> V transposed into vt (B*H, 256, T)
// EPI 1: out f32 = acc + bias[col] + res[idx]
// EPI 2: out bf16 = relu(acc + bias[col])
template<int EPI, int BN>
__global__ __launch_bounds__(256) void gemm_k(const __hip_bfloat16* __restrict__ A,
                                              const __hip_bfloat16* __restrict__ Bt,
                                              int M, int N, int Kd,
                                              const float* __restrict__ bias,
                                              const float* __restrict__ res,
                                              void* __restrict__ outp, float scale,
                                              __hip_bfloat16* __restrict__ vtp) {
    constexpr int NF = BN / 32;
    constexpr int BPHYS = BN / 4;            // physical 512-B rows in B tile
    constexpr int SWZM = (BPHYS - 1) & 31;
    __shared__ short sA[2][128 * 64];        // 16 KB per buffer
    __shared__ short sB[2][BN * 64];
    int tid = threadIdx.x, lane = tid & 63, wave = tid >> 6;
    int l15 = lane & 15, g = lane >> 4;
    int m0 = blockIdx.y * 128, n0 = blockIdx.x * BN;
    int wm = (wave >> 1) * 64, wn = (wave & 1) * (BN / 2);
    f32x4 acc[4][NF] = {};
    const int NT = Kd >> 6;

    auto STAGE = [&](int kt, int buf) {
        #pragma unroll
        for (int c = 0; c < 4; ++c) {            // A: 128 rows x 128 B = 16 KB
            int L = c * 4096 + tid * 16;
            int phys = L >> 9;                   // 0..31
            int vp = ((L >> 4) & 31) ^ phys;     // unswizzled slot
            int row = (vp >> 3) * 32 + phys;
            gld_lds16(A + (size_t)(m0 + row) * Kd + kt * 64 + (vp & 7) * 8,
                      (char*)sA[buf] + L);
        }
        #pragma unroll
        for (int c = 0; c < BN / 32; ++c) {      // B: BN rows x 128 B
            int L = c * 4096 + tid * 16;
            int phys = L >> 9;                   // 0..BPHYS-1
            int vp = ((L >> 4) & 31) ^ (phys & SWZM);
            int row = (vp >> 3) * BPHYS + phys;
            gld_lds16(Bt + (size_t)(n0 + row) * Kd + kt * 64 + (vp & 7) * 8,
                      (char*)sB[buf] + L);
        }
    };

    STAGE(0, 0);
    asm volatile("s_waitcnt vmcnt(0)" ::: "memory");
    __syncthreads();
    int cur = 0;
    for (int kt = 0; kt < NT; ++kt) {
        if (kt + 1 < NT) STAGE(kt + 1, cur ^ 1);   // issue next tile early
        #pragma unroll
        for (int kk = 0; kk < 2; ++kk) {
            bf16x8 af[4], bfr[NF];
            #pragma unroll
            for (int mf = 0; mf < 4; ++mf) {
                int R = wm + mf * 16 + l15;
                int v = (((R >> 5) << 3) + (kk << 2) + g) ^ (R & 31);
                af[mf] = *(const bf16x8*)((char*)sA[cur] + ((R & 31) << 9) + (v << 4));
            }
            #pragma unroll
            for (int nf = 0; nf < NF; ++nf) {
                int R = wn + nf * 16 + l15;
                int v = ((R / BPHYS) * 8 + (kk << 2) + g) ^ (R & SWZM);
                bfr[nf] = *(const bf16x8*)((char*)sB[cur] + ((R % BPHYS) << 9) + (v << 4));
            }
            #pragma unroll
            for (int mf = 0; mf < 4; ++mf)
                #pragma unroll
                for (int nf = 0; nf < NF; ++nf)
                    acc[mf][nf] = __builtin_amdgcn_mfma_f32_16x16x32_bf16(af[mf], bfr[nf], acc[mf][nf], 0, 0, 0);
        }
        asm volatile("s_waitcnt vmcnt(0)" ::: "memory");   // next tile landed
        __syncthreads();                                    // all waves done with cur
        cur ^= 1;
    }

    #pragma unroll
    for (int mf = 0; mf < 4; ++mf) {
        int rowb = m0 + wm + mf * 16 + g * 4;
        #pragma unroll
        for (int nf = 0; nf < NF; ++nf) {
            int col = n0 + wn + nf * 16 + l15;
            if (EPI == 0) {
                if (col < 4096) {
                    #pragma unroll
                    for (int r = 0; r < 4; ++r)
                        ((__hip_bfloat16*)outp)[(size_t)(rowb + r) * QKS + col] =
                            __float2bfloat16(acc[mf][nf][r] * scale);
                } else {
                    int hv = col - 4096, h = hv >> 8, d = hv & 255;
                    int b = rowb >> 11, t = rowb & 2047;
                    ushort4 w;
                    w.x = __bfloat16_as_ushort(__float2bfloat16(acc[mf][nf][0]));
                    w.y = __bfloat16_as_ushort(__float2bfloat16(acc[mf][nf][1]));
                    w.z = __bfloat16_as_ushort(__float2bfloat16(acc[mf][nf][2]));
                    w.w = __bfloat16_as_ushort(__float2bfloat16(acc[mf][nf][3]));
                    *(ushort4*)(vtp + ((size_t)((b * 8 + h) * 256 + d)) * TT + t) = w;
                }
            } else {
                #pragma unroll
                for (int r = 0; r < 4; ++r) {
                    float v = acc[mf][nf][r];
                    size_t idx = (size_t)(rowb + r) * N + col;
                    if (EPI == 1) {
                        ((float*)outp)[idx] = v + bias[col] + res[idx];
                    } else {
                        v += bias[col];
                        ((__hip_bfloat16*)outp)[idx] = __float2bfloat16(v > 0.0f ? v : 0.0f);
                    }
                }
            }
        }
    }
}

// ---------------- flash attention: 8 waves x 16 q-rows, dbuf LDS, swapped-QK softmax ----
// Round-8 structure with R11/R12-proven conflict-free LDS addressing:
// K [64 s][512B]: granule q holds K[s][(q ^ (s&31))*8e]  (full 5-bit XOR).
// V packed [64 R][512B]: granule q holds V^T[d=(gl>>3)*64+R][s-oct gl&7], gl=q^(R&31).
__global__ __launch_bounds__(512, 2) void attn_k(const __hip_bfloat16* __restrict__ QK,
                                                 const __hip_bfloat16* __restrict__ VT,
                                                 __hip_bfloat16* __restrict__ O) {
    __shared__ char Kl[2][32768];
    __shared__ char Vl[2][32768];
    __shared__ char Pl[8][2048];     // per-wave P: [16 q][64 s] bf16, XOR-swizzled
    int tid = threadIdx.x, lane = tid & 63, wave = tid >> 6;
    int id = blockIdx.x;
    int xcd = id & 7, w = id >> 3;            // w: 0..31
    int bh = xcd * 4 + (w >> 3);
    int jtp = w & 7;
    int b = bh >> 3, h = bh & 7;
    const __hip_bfloat16* Qb = QK + (size_t)b * TT * QKS + h * KK;
    const __hip_bfloat16* Kb = Qb + 2048;
    const __hip_bfloat16* Vtb = VT + (size_t)bh * KK * TT;

    int l15 = lane & 15, g = lane >> 4;
    int koff = g * 8;            // elements
    int koffB = g * 16;          // bytes
    int pswz = (l15 & 7) << 4;   // P-tile swizzle for this lane's q-row

    auto STAGE = [&](int s0, int buf) {
        #pragma unroll
        for (int rd = 0; rd < 4; ++rd) {        // K: 64 rows x 512 B
            int L = rd * 8192 + tid * 16;
            int row = L >> 9;
            int cb = (L & 511) ^ ((row & 31) << 4);
            gld_lds16((const char*)(Kb + (size_t)(s0 + row) * QKS) + cb,
                      Kl[buf] + rd * 8192 + wave * 1024);
        }
        #pragma unroll
        for (int rd = 0; rd < 4; ++rd) {        // V: packed [64 R][512 B]
            int L = rd * 8192 + tid * 16;
            int R = L >> 9;
            int q = (L >> 4) & 31;
            int gl = q ^ (R & 31);
            int d = (gl >> 3) * 64 + R;
            gld_lds16((const char*)(Vtb + (size_t)d * TT + s0 + (gl & 7) * 8),
                      Vl[buf] + rd * 8192 + wave * 1024);
        }
    };

    #pragma unroll 1
    for (int half = 0; half < 2; ++half) {
        int jt = (half == 0) ? jtp : 15 - jtp;
        int q0 = jt * 128;
        int rowbase = q0 + wave * 16;
        bf16x8 qf[8];
        #pragma unroll
        for (int kk = 0; kk < 8; ++kk)
            qf[kk] = *(const bf16x8*)(Qb + (size_t)(rowbase + l15) * QKS + kk * 32 + koff);

        f32x4 Oa[16] = {};
        float mrow = -__builtin_inff();
        float lrow = 0.f;

        STAGE(0, 0);
        asm volatile("s_waitcnt vmcnt(0)" ::: "memory");
        __syncthreads();
        int cur = 0;
        const int niter = 2 * jt + 2;

        #pragma unroll 1
        for (int i = 0; i < niter; ++i) {
            int s0 = i * 64;
            if (i + 1 < niter) STAGE(s0 + 64, cur ^ 1);   // prefetch into other buffer

            if (s0 <= rowbase + 15) {                     // wave has unmasked rows
                // ---- QK^T swapped: S = K-tile x Q-frag (lane col = q = l15)
                f32x4 S[4] = {};
                __builtin_amdgcn_s_setprio(1);
                #pragma unroll
                for (int nf = 0; nf < 4; ++nf) {
                    int r = nf * 16 + l15;
                    int swz = (r & 31) << 4;
                    #pragma unroll
                    for (int kk = 0; kk < 8; ++kk) {
                        bf16x8 kf = *(const bf16x8*)(Kl[cur] + r * 512 + ((kk * 64 + koffB) ^ swz));
                        S[nf] = __builtin_amdgcn_mfma_f32_16x16x32_bf16(kf, qf[kk], S[nf], 0, 0, 0);
                    }
                }
                __builtin_amdgcn_s_setprio(0);
                if (s0 + 63 > rowbase) {                  // causal: S row = s, col = q
                    int qg = rowbase + l15;
                    #pragma unroll
                    for (int nf = 0; nf < 4; ++nf)
                        #pragma unroll
                        for (int r = 0; r < 4; ++r) {
                            int sg = s0 + nf * 16 + g * 4 + r;
                            if (sg > qg) S[nf][r] = -__builtin_inff();
                        }
                }
                // ---- softmax (exp2 domain), stats lane-local in l15
                float mx = S[0][0];
                #pragma unroll
                for (int nf = 0; nf < 4; ++nf)
                    #pragma unroll
                    for (int r = 0; r < 4; ++r) mx = fmaxf(mx, S[nf][r]);
                mx = fmaxf(mx, __shfl_xor(mx, 16));
                mx = fmaxf(mx, __shfl_xor(mx, 32));
                if (__any(mx > mrow + 8.0f)) {            // defer-max rescale
                    float mn = fmaxf(mrow, mx);
                    float alpha = exp2f(mrow - mn);
                    mrow = mn;
                    lrow *= alpha;
                    float al[4];
                    #pragma unroll
                    for (int r = 0; r < 4; ++r) al[r] = __shfl(alpha, (g << 2) + r);
                    #pragma unroll
                    for (int nf2 = 0; nf2 < 16; ++nf2)
                        #pragma unroll
                        for (int r = 0; r < 4; ++r) Oa[nf2][r] *= al[r];
                }
                float ps = 0.f;
                #pragma unroll
                for (int nf = 0; nf < 4; ++nf)
                    #pragma unroll
                    for (int r = 0; r < 4; ++r) {
                        float p = exp2f(S[nf][r] - mrow);
                        S[nf][r] = p; ps += p;
                    }
                ps += __shfl_xor(ps, 16);
                ps += __shfl_xor(ps, 32);
                lrow += ps;
                // ---- P -> LDS [q=l15][s], b64 packed writes, swizzled
                #pragma unroll
                for (int nf = 0; nf < 4; ++nf) {
                    uint2 pk2;
                    pk2.x = (unsigned)__bfloat16_as_ushort(__float2bfloat16(S[nf][0]))
                          | ((unsigned)__bfloat16_as_ushort(__float2bfloat16(S[nf][1])) << 16);
                    pk2.y = (unsigned)__bfloat16_as_ushort(__float2bfloat16(S[nf][2]))
                          | ((unsigned)__bfloat16_as_ushort(__float2bfloat16(S[nf][3])) << 16);
                    *(uint2*)(Pl[wave] + l15 * 128 + ((nf * 32 + g * 8) ^ pswz)) = pk2;
                }
                // ---- PV: O += P @ V  (V packed rows)
                bf16x8 pa[2];
                #pragma unroll
                for (int kk2 = 0; kk2 < 2; ++kk2)
                    pa[kk2] = *(const bf16x8*)(Pl[wave] + l15 * 128 + ((kk2 * 64 + koffB) ^ pswz));
                __builtin_amdgcn_s_setprio(1);
                #pragma unroll
                for (int nf2 = 0; nf2 < 16; ++nf2) {
                    int d = nf2 * 16 + l15;
                    int R = d & 63;
                    #pragma unroll
                    for (int kk2 = 0; kk2 < 2; ++kk2) {
                        int gl = ((d >> 6) << 3) | (kk2 * 4 + g);
                        int q = gl ^ (R & 31);
                        bf16x8 vb = *(const bf16x8*)(Vl[cur] + R * 512 + (q << 4));
                        Oa[nf2] = __builtin_amdgcn_mfma_f32_16x16x32_bf16(pa[kk2], vb, Oa[nf2], 0, 0, 0);
                    }
                }
                __builtin_amdgcn_s_setprio(0);
            }
            asm volatile("s_waitcnt vmcnt(0)" ::: "memory");   // own prefetch landed
            __syncthreads();                                    // all waves done + staged
            cur ^= 1;
        }
        // ---- write this q-tile's output
        float rcp_ = 1.0f / lrow;
        float rc[4];
        #pragma unroll
        for (int r = 0; r < 4; ++r) rc[r] = __shfl(rcp_, (g << 2) + r);
        #pragma unroll
        for (int nf2 = 0; nf2 < 16; ++nf2) {
            int col = nf2 * 16 + l15;
            #pragma unroll
            for (int r = 0; r < 4; ++r) {
                int t = rowbase + g * 4 + r;
                O[((size_t)b * TT + t) * 2048 + h * KK + col] = __float2bfloat16(Oa[nf2][r] * rc[r]);
            }
        }
    }
}

// ---------------- row LayerNorm over K=256, 4 rows/block ----------------
__global__ __launch_bounds__(256) void layernorm_k(const float* __restrict__ y,
                                                   const float* __restrict__ g,
                                                   const float* __restrict__ be,
                                                   float* __restrict__ out_f,
                                                   __hip_bfloat16* __restrict__ out_b) {
    int row = blockIdx.x * 4 + (threadIdx.x >> 6);
    int lane = threadIdx.x & 63;
    float4 v = *(const float4*)(y + (size_t)row * 256 + lane * 4);
    float s = v.x + v.y + v.z + v.w;
    #pragma unroll
    for (int d = 1; d < 64; d <<= 1) s += __shfl_xor(s, d);
    float mu = s * (1.0f / 256.0f);
    float dx = v.x - mu, dy = v.y - mu, dz = v.z - mu, dw = v.w - mu;
    float q = dx * dx + dy * dy + dz * dz + dw * dw;
    #pragma unroll
    for (int d = 1; d < 64; d <<= 1) q += __shfl_xor(q, d);
    float rs = rsqrtf(q * (1.0f / 256.0f) + 1e-5f);
    float4 gg = *(const float4*)(g + lane * 4);
    float4 bb = *(const float4*)(be + lane * 4);
    float4 o;
    o.x = dx * rs * gg.x + bb.x;
    o.y = dy * rs * gg.y + bb.y;
    o.z = dz * rs * gg.z + bb.z;
    o.w = dw * rs * gg.w + bb.w;
    *(float4*)(out_f + (size_t)row * 256 + lane * 4) = o;
    if (out_b) {
        size_t i = (size_t)row * 256 + lane * 4;
        out_b[i + 0] = __float2bfloat16(o.x);
        out_b[i + 1] = __float2bfloat16(o.y);
        out_b[i + 2] = __float2bfloat16(o.z);
        out_b[i + 3] = __float2bfloat16(o.w);
    }
}

extern "C" void kernel_launch(void* const* d_in, const int* in_sizes, int n_in,
                              void* d_out, int out_size, void* d_ws, size_t ws_size,
                              hipStream_t stream) {
    const float* x  = (const float*)d_in[0];
    const float* wq = (const float*)d_in[1];
    const float* wk = (const float*)d_in[2];
    const float* wv = (const float*)d_in[3];
    const float* wu = (const float*)d_in[4];
    const float* bu = (const float*)d_in[5];
    const float* w1 = (const float*)d_in[6];
    const float* b1 = (const float*)d_in[7];
    const float* w2 = (const float*)d_in[8];
    const float* b2 = (const float*)d_in[9];
    const float* g1 = (const float*)d_in[10];
    const float* be1 = (const float*)d_in[11];
    const float* g2 = (const float*)d_in[12];
    const float* be2 = (const float*)d_in[13];

    char* p = (char*)d_ws;
    auto alloc = [&](size_t bytes) { char* r = p; p += bytes; return r; };
    __hip_bfloat16* xb    = (__hip_bfloat16*)alloc((size_t)MM * KK * 2);
    __hip_bfloat16* wqkvT = (__hip_bfloat16*)alloc((size_t)NQKV * KK * 2);
    __hip_bfloat16* wuT   = (__hip_bfloat16*)alloc((size_t)KK * 2048 * 2);
    __hip_bfloat16* w1T   = (__hip_bfloat16*)alloc((size_t)1024 * KK * 2);
    __hip_bfloat16* w2T   = (__hip_bfloat16*)alloc((size_t)KK * 1024 * 2);
    __hip_bfloat16* qk    = (__hip_bfloat16*)alloc((size_t)MM * QKS * 2);
    __hip_bfloat16* vt    = (__hip_bfloat16*)alloc((size_t)32 * KK * TT * 2);
    __hip_bfloat16* attn  = (__hip_bfloat16*)alloc((size_t)MM * 2048 * 2);
    float*          y1    = (float*)alloc((size_t)MM * KK * 4);
    float*          x1    = (float*)alloc((size_t)MM * KK * 4);
    __hip_bfloat16* x1b   = (__hip_bfloat16*)alloc((size_t)MM * KK * 2);
    __hip_bfloat16* hid   = (__hip_bfloat16*)alloc((size_t)MM * 1024 * 2);
    float*          y2    = (float*)alloc((size_t)MM * KK * 4);

    // 1. fused prep (cvt + 6 transposes)
    prep_k<<<4608, 256, 0, stream>>>(x, xb, wq, wk, wv, wu, w1, w2,
                                     wqkvT, wuT, w1T, w2T);

    // 2. QKV projection; q/k scale 0.25*sqrt(log2 e); V fused-transposed into vt
    gemm_k<0, 128><<<dim3(NQKV / 128, MM / 128), 256, 0, stream>>>(
        xb, wqkvT, MM, NQKV, 256, nullptr, nullptr, qk, 0.3002806f, vt);

    // 3. flash attention
    attn_k<<<dim3(256), 512, 0, stream>>>(qk, vt, attn);

    // 4. attn-out proj + residual -> y1 (f32); LN1 -> x1 + x1b
    gemm_k<1, 64><<<dim3(4, MM / 128), 256, 0, stream>>>(
        attn, wuT, MM, 256, 2048, bu, x, y1, 1.0f, nullptr);
    layernorm_k<<<MM / 4, 256, 0, stream>>>(y1, g1, be1, x1, x1b);

    // 5. FFN1: relu(x1b @ w1 + b1) -> hid (bf16)
    gemm_k<2, 128><<<dim3(8, MM / 128), 256, 0, stream>>>(
        x1b, w1T, MM, 1024, 256, b1, nullptr, hid, 1.0f, nullptr);

    // 6. FFN2 + residual -> y2; LN2 -> d_out
    gemm_k<1, 64><<<dim3(4, MM / 128), 256, 0, stream>>>(
        hid, w2T, MM, 256, 1024, b2, x1, y2, 1.0f, nullptr);
    layernorm_k<<<MM / 4, 256, 0, stream>>>(y2, g2, be2, (float*)d_out, nullptr);
}

// Round 16
// 240.486 us; speedup vs baseline: 1.1870x; 1.0508x over previous
//
#include <hip/hip_runtime.h>
#include <hip/hip_bf16.h>

#define TT 2048
#define BB 4
#define HH 8
#define KK 256
#define MM (BB*TT)      // 8192 tokens
#define NQKV 6144
#define QKS 4096        // packed Q|K row stride

typedef __attribute__((ext_vector_type(8))) short bf16x8;
typedef __attribute__((ext_vector_type(4))) float f32x4;

__device__ __forceinline__ void gld_lds16(const void* g, void* lds) {
    __builtin_amdgcn_global_load_lds(
        (const __attribute__((address_space(1))) unsigned int*)g,
        (__attribute__((address_space(3))) unsigned int*)lds, 16, 0, 0);
}

// ---------------- fused prep: x->bf16 + 6 weight transpose-converts ----------------
__global__ __launch_bounds__(256) void prep_k(
    const float* __restrict__ x, __hip_bfloat16* __restrict__ xb,
    const float* __restrict__ wq, const float* __restrict__ wk,
    const float* __restrict__ wv, const float* __restrict__ wu,
    const float* __restrict__ w1, const float* __restrict__ w2,
    __hip_bfloat16* __restrict__ wqkvT, __hip_bfloat16* __restrict__ wuT,
    __hip_bfloat16* __restrict__ w1T, __hip_bfloat16* __restrict__ w2T) {
    __shared__ float tile[32][33];
    int bid = blockIdx.x, tid = threadIdx.x;
    if (bid < 2048) {
        int i = (bid * 256 + tid) * 4;
        float4 v = *(const float4*)(x + i);
        xb[i + 0] = __float2bfloat16(v.x);
        xb[i + 1] = __float2bfloat16(v.y);
        xb[i + 2] = __float2bfloat16(v.z);
        xb[i + 3] = __float2bfloat16(v.w);
        return;
    }
    int t = bid - 2048;
    const float* in; __hip_bfloat16* out; int R, C, cx, ry;
    if (t < 1536) {                         // wq / wk / wv: 256 x 2048
        int j = t >> 9, u = t & 511;
        in = (j == 0) ? wq : (j == 1 ? wk : wv);
        out = wqkvT + (size_t)j * 2048 * 256;
        R = 256; C = 2048; cx = u & 63; ry = u >> 6;
    } else if (t < 2048) {                  // wu: 2048 x 256
        int u = t - 1536; in = wu; out = wuT; R = 2048; C = 256; cx = u & 7; ry = u >> 3;
    } else if (t < 2304) {                  // w1: 256 x 1024
        int u = t - 2048; in = w1; out = w1T; R = 256; C = 1024; cx = u & 31; ry = u >> 5;
    } else {                                // w2: 1024 x 256
        int u = t - 2304; in = w2; out = w2T; R = 1024; C = 256; cx = u & 7; ry = u >> 3;
    }
    int c0 = cx * 32, r0 = ry * 32;
    int tx = tid & 31, ty = tid >> 5;
    #pragma unroll
    for (int i = ty; i < 32; i += 8)
        tile[i][tx] = in[(size_t)(r0 + i) * C + c0 + tx];
    __syncthreads();
    #pragma unroll
    for (int i = ty; i < 32; i += 8)
        out[(size_t)(c0 + i) * R + r0 + tx] = __float2bfloat16(tile[tx][i]);
}

// ---------------- GEMM, 2-phase pipelined, BK=64, packed-512B-row LDS ----------------
// EPI 0: QKV fused epilogue: col<4096 -> qk (stride 4096, *scale);
//        col>=4096 -> V transposed into vt (B*H, 256, T)
// EPI 1: out f32 = acc + bias[col] + res[idx]
// EPI 2: out bf16 = relu(acc + bias[col])
template<int EPI, int BN>
__global__ __launch_bounds__(256) void gemm_k(const __hip_bfloat16* __restrict__ A,
                                              const __hip_bfloat16* __restrict__ Bt,
                                              int M, int N, int Kd,
                                              const float* __restrict__ bias,
                                              const float* __restrict__ res,
                                              void* __restrict__ outp, float scale,
                                              __hip_bfloat16* __restrict__ vtp) {
    constexpr int NF = BN / 32;
    constexpr int BPHYS = BN / 4;            // physical 512-B rows in B tile
    constexpr int SWZM = (BPHYS - 1) & 31;
    __shared__ short sA[2][128 * 64];        // 16 KB per buffer
    __shared__ short sB[2][BN * 64];
    int tid = threadIdx.x, lane = tid & 63, wave = tid >> 6;
    int l15 = lane & 15, g = lane >> 4;
    int m0 = blockIdx.y * 128, n0 = blockIdx.x * BN;
    int wm = (wave >> 1) * 64, wn = (wave & 1) * (BN / 2);
    f32x4 acc[4][NF] = {};
    const int NT = Kd >> 6;

    auto STAGE = [&](int kt, int buf) {
        #pragma unroll
        for (int c = 0; c < 4; ++c) {            // A: 128 rows x 128 B = 16 KB
            int L = c * 4096 + tid * 16;
            int phys = L >> 9;                   // 0..31
            int vp = ((L >> 4) & 31) ^ phys;     // unswizzled slot
            int row = (vp >> 3) * 32 + phys;
            gld_lds16(A + (size_t)(m0 + row) * Kd + kt * 64 + (vp & 7) * 8,
                      (char*)sA[buf] + L);
        }
        #pragma unroll
        for (int c = 0; c < BN / 32; ++c) {      // B: BN rows x 128 B
            int L = c * 4096 + tid * 16;
            int phys = L >> 9;                   // 0..BPHYS-1
            int vp = ((L >> 4) & 31) ^ (phys & SWZM);
            int row = (vp >> 3) * BPHYS + phys;
            gld_lds16(Bt + (size_t)(n0 + row) * Kd + kt * 64 + (vp & 7) * 8,
                      (char*)sB[buf] + L);
        }
    };

    STAGE(0, 0);
    asm volatile("s_waitcnt vmcnt(0)" ::: "memory");
    __syncthreads();
    int cur = 0;
    for (int kt = 0; kt < NT; ++kt) {
        if (kt + 1 < NT) STAGE(kt + 1, cur ^ 1);   // issue next tile early
        #pragma unroll
        for (int kk = 0; kk < 2; ++kk) {
            bf16x8 af[4], bfr[NF];
            #pragma unroll
            for (int mf = 0; mf < 4; ++mf) {
                int R = wm + mf * 16 + l15;
                int v = (((R >> 5) << 3) + (kk << 2) + g) ^ (R & 31);
                af[mf] = *(const bf16x8*)((char*)sA[cur] + ((R & 31) << 9) + (v << 4));
            }
            #pragma unroll
            for (int nf = 0; nf < NF; ++nf) {
                int R = wn + nf * 16 + l15;
                int v = ((R / BPHYS) * 8 + (kk << 2) + g) ^ (R & SWZM);
                bfr[nf] = *(const bf16x8*)((char*)sB[cur] + ((R % BPHYS) << 9) + (v << 4));
            }
            #pragma unroll
            for (int mf = 0; mf < 4; ++mf)
                #pragma unroll
                for (int nf = 0; nf < NF; ++nf)
                    acc[mf][nf] = __builtin_amdgcn_mfma_f32_16x16x32_bf16(af[mf], bfr[nf], acc[mf][nf], 0, 0, 0);
        }
        asm volatile("s_waitcnt vmcnt(0)" ::: "memory");   // next tile landed
        __syncthreads();                                    // all waves done with cur
        cur ^= 1;
    }

    #pragma unroll
    for (int mf = 0; mf < 4; ++mf) {
        int rowb = m0 + wm + mf * 16 + g * 4;
        #pragma unroll
        for (int nf = 0; nf < NF; ++nf) {
            int col = n0 + wn + nf * 16 + l15;
            if (EPI == 0) {
                if (col < 4096) {
                    #pragma unroll
                    for (int r = 0; r < 4; ++r)
                        ((__hip_bfloat16*)outp)[(size_t)(rowb + r) * QKS + col] =
                            __float2bfloat16(acc[mf][nf][r] * scale);
                } else {
                    int hv = col - 4096, h = hv >> 8, d = hv & 255;
                    int b = rowb >> 11, t = rowb & 2047;
                    ushort4 w;
                    w.x = __bfloat16_as_ushort(__float2bfloat16(acc[mf][nf][0]));
                    w.y = __bfloat16_as_ushort(__float2bfloat16(acc[mf][nf][1]));
                    w.z = __bfloat16_as_ushort(__float2bfloat16(acc[mf][nf][2]));
                    w.w = __bfloat16_as_ushort(__float2bfloat16(acc[mf][nf][3]));
                    *(ushort4*)(vtp + ((size_t)((b * 8 + h) * 256 + d)) * TT + t) = w;
                }
            } else {
                #pragma unroll
                for (int r = 0; r < 4; ++r) {
                    float v = acc[mf][nf][r];
                    size_t idx = (size_t)(rowb + r) * N + col;
                    if (EPI == 1) {
                        ((float*)outp)[idx] = v + bias[col] + res[idx];
                    } else {
                        v += bias[col];
                        ((__hip_bfloat16*)outp)[idx] = __float2bfloat16(v > 0.0f ? v : 0.0f);
                    }
                }
            }
        }
    }
}

// ---------------- flash attention: 8 waves x 16 q-rows, dbuf LDS, swapped-QK softmax ----
// Round-8 structure. K swizzle widened to (row&31)<<4 (same instruction count,
// 2-way banks instead of 4-way); V kept at round-8 cheap addressing
// ([256 R][128B], (row&7)<<4) -- round-15 showed the conflict-free V layout's
// extra VALU cost exceeds its conflict savings.
__global__ __launch_bounds__(512, 2) void attn_k(const __hip_bfloat16* __restrict__ QK,
                                                 const __hip_bfloat16* __restrict__ VT,
                                                 __hip_bfloat16* __restrict__ O) {
    __shared__ char Kl[2][32768];
    __shared__ char Vl[2][32768];
    __shared__ char Pl[8][2048];     // per-wave P: [16 q][64 s] bf16, XOR-swizzled
    int tid = threadIdx.x, lane = tid & 63, wave = tid >> 6;
    int id = blockIdx.x;
    int xcd = id & 7, w = id >> 3;            // w: 0..31
    int bh = xcd * 4 + (w >> 3);
    int jtp = w & 7;
    int b = bh >> 3, h = bh & 7;
    const __hip_bfloat16* Qb = QK + (size_t)b * TT * QKS + h * KK;
    const __hip_bfloat16* Kb = Qb + 2048;
    const __hip_bfloat16* Vtb = VT + (size_t)bh * KK * TT;

    int l15 = lane & 15, g = lane >> 4;
    int koff = g * 8;            // elements
    int koffB = g * 16;          // bytes
    int pswz = (l15 & 7) << 4;   // P-tile swizzle for this lane's q-row

    auto STAGE = [&](int s0, int buf) {
        #pragma unroll
        for (int rd = 0; rd < 4; ++rd) {        // K: 64 rows x 512 B, full 5-bit XOR
            int L = rd * 8192 + tid * 16;
            int row = L >> 9;
            int cb = (L & 511) ^ ((row & 31) << 4);
            gld_lds16((const char*)(Kb + (size_t)(s0 + row) * QKS) + cb,
                      Kl[buf] + rd * 8192 + wave * 1024);
        }
        #pragma unroll
        for (int rd = 0; rd < 4; ++rd) {        // V: 256 rows x 128 B (round-8 cheap)
            int L = rd * 8192 + tid * 16;
            int row = L >> 7;
            int cb = (L & 127) ^ ((row & 7) << 4);
            gld_lds16((const char*)(Vtb + (size_t)row * TT + s0) + cb,
                      Vl[buf] + rd * 8192 + wave * 1024);
        }
    };

    #pragma unroll 1
    for (int half = 0; half < 2; ++half) {
        int jt = (half == 0) ? jtp : 15 - jtp;
        int q0 = jt * 128;
        int rowbase = q0 + wave * 16;
        bf16x8 qf[8];
        #pragma unroll
        for (int kk = 0; kk < 8; ++kk)
            qf[kk] = *(const bf16x8*)(Qb + (size_t)(rowbase + l15) * QKS + kk * 32 + koff);

        f32x4 Oa[16] = {};
        float mrow = -__builtin_inff();
        float lrow = 0.f;

        STAGE(0, 0);
        asm volatile("s_waitcnt vmcnt(0)" ::: "memory");
        __syncthreads();
        int cur = 0;
        const int niter = 2 * jt + 2;

        #pragma unroll 1
        for (int i = 0; i < niter; ++i) {
            int s0 = i * 64;
            if (i + 1 < niter) STAGE(s0 + 64, cur ^ 1);   // prefetch into other buffer

            if (s0 <= rowbase + 15) {                     // wave has unmasked rows
                // ---- QK^T swapped: S = K-tile x Q-frag (lane col = q = l15)
                f32x4 S[4] = {};
                __builtin_amdgcn_s_setprio(1);
                #pragma unroll
                for (int nf = 0; nf < 4; ++nf) {
                    int r = nf * 16 + l15;
                    int swz = (r & 31) << 4;
                    #pragma unroll
                    for (int kk = 0; kk < 8; ++kk) {
                        bf16x8 kf = *(const bf16x8*)(Kl[cur] + r * 512 + ((kk * 64 + koffB) ^ swz));
                        S[nf] = __builtin_amdgcn_mfma_f32_16x16x32_bf16(kf, qf[kk], S[nf], 0, 0, 0);
                    }
                }
                __builtin_amdgcn_s_setprio(0);
                if (s0 + 63 > rowbase) {                  // causal: S row = s, col = q
                    int qg = rowbase + l15;
                    #pragma unroll
                    for (int nf = 0; nf < 4; ++nf)
                        #pragma unroll
                        for (int r = 0; r < 4; ++r) {
                            int sg = s0 + nf * 16 + g * 4 + r;
                            if (sg > qg) S[nf][r] = -__builtin_inff();
                        }
                }
                // ---- softmax (exp2 domain), stats lane-local in l15
                float mx = S[0][0];
                #pragma unroll
                for (int nf = 0; nf < 4; ++nf)
                    #pragma unroll
                    for (int r = 0; r < 4; ++r) mx = fmaxf(mx, S[nf][r]);
                mx = fmaxf(mx, __shfl_xor(mx, 16));
                mx = fmaxf(mx, __shfl_xor(mx, 32));
                if (__any(mx > mrow + 8.0f)) {            // defer-max rescale
                    float mn = fmaxf(mrow, mx);
                    float alpha = exp2f(mrow - mn);
                    mrow = mn;
                    lrow *= alpha;
                    float al[4];
                    #pragma unroll
                    for (int r = 0; r < 4; ++r) al[r] = __shfl(alpha, (g << 2) + r);
                    #pragma unroll
                    for (int nf2 = 0; nf2 < 16; ++nf2)
                        #pragma unroll
                        for (int r = 0; r < 4; ++r) Oa[nf2][r] *= al[r];
                }
                float ps = 0.f;
                #pragma unroll
                for (int nf = 0; nf < 4; ++nf)
                    #pragma unroll
                    for (int r = 0; r < 4; ++r) {
                        float p = exp2f(S[nf][r] - mrow);
                        S[nf][r] = p; ps += p;
                    }
                ps += __shfl_xor(ps, 16);
                ps += __shfl_xor(ps, 32);
                lrow += ps;
                // ---- P -> LDS [q=l15][s], b64 packed writes, swizzled
                #pragma unroll
                for (int nf = 0; nf < 4; ++nf) {
                    uint2 pk2;
                    pk2.x = (unsigned)__bfloat16_as_ushort(__float2bfloat16(S[nf][0]))
                          | ((unsigned)__bfloat16_as_ushort(__float2bfloat16(S[nf][1])) << 16);
                    pk2.y = (unsigned)__bfloat16_as_ushort(__float2bfloat16(S[nf][2]))
                          | ((unsigned)__bfloat16_as_ushort(__float2bfloat16(S[nf][3])) << 16);
                    *(uint2*)(Pl[wave] + l15 * 128 + ((nf * 32 + g * 8) ^ pswz)) = pk2;
                }
                // ---- PV: O += P @ V
                bf16x8 pa[2];
                #pragma unroll
                for (int kk2 = 0; kk2 < 2; ++kk2)
                    pa[kk2] = *(const bf16x8*)(Pl[wave] + l15 * 128 + ((kk2 * 64 + koffB) ^ pswz));
                __builtin_amdgcn_s_setprio(1);
                #pragma unroll
                for (int nf2 = 0; nf2 < 16; ++nf2) {
                    int r = nf2 * 16 + l15;
                    int swz = (r & 7) << 4;
                    #pragma unroll
                    for (int kk2 = 0; kk2 < 2; ++kk2) {
                        bf16x8 vb = *(const bf16x8*)(Vl[cur] + r * 128 + ((kk2 * 64 + koffB) ^ swz));
                        Oa[nf2] = __builtin_amdgcn_mfma_f32_16x16x32_bf16(pa[kk2], vb, Oa[nf2], 0, 0, 0);
                    }
                }
                __builtin_amdgcn_s_setprio(0);
            }
            asm volatile("s_waitcnt vmcnt(0)" ::: "memory");   // own prefetch landed
            __syncthreads();                                    // all waves done + staged
            cur ^= 1;
        }
        // ---- write this q-tile's output
        float rcp_ = 1.0f / lrow;
        float rc[4];
        #pragma unroll
        for (int r = 0; r < 4; ++r) rc[r] = __shfl(rcp_, (g << 2) + r);
        #pragma unroll
        for (int nf2 = 0; nf2 < 16; ++nf2) {
            int col = nf2 * 16 + l15;
            #pragma unroll
            for (int r = 0; r < 4; ++r) {
                int t = rowbase + g * 4 + r;
                O[((size_t)b * TT + t) * 2048 + h * KK + col] = __float2bfloat16(Oa[nf2][r] * rc[r]);
            }
        }
    }
}

// ---------------- row LayerNorm over K=256, 4 rows/block ----------------
__global__ __launch_bounds__(256) void layernorm_k(const float* __restrict__ y,
                                                   const float* __restrict__ g,
                                                   const float* __restrict__ be,
                                                   float* __restrict__ out_f,
                                                   __hip_bfloat16* __restrict__ out_b) {
    int row = blockIdx.x * 4 + (threadIdx.x >> 6);
    int lane = threadIdx.x & 63;
    float4 v = *(const float4*)(y + (size_t)row * 256 + lane * 4);
    float s = v.x + v.y + v.z + v.w;
    #pragma unroll
    for (int d = 1; d < 64; d <<= 1) s += __shfl_xor(s, d);
    float mu = s * (1.0f / 256.0f);
    float dx = v.x - mu, dy = v.y - mu, dz = v.z - mu, dw = v.w - mu;
    float q = dx * dx + dy * dy + dz * dz + dw * dw;
    #pragma unroll
    for (int d = 1; d < 64; d <<= 1) q += __shfl_xor(q, d);
    float rs = rsqrtf(q * (1.0f / 256.0f) + 1e-5f);
    float4 gg = *(const float4*)(g + lane * 4);
    float4 bb = *(const float4*)(be + lane * 4);
    float4 o;
    o.x = dx * rs * gg.x + bb.x;
    o.y = dy * rs * gg.y + bb.y;
    o.z = dz * rs * gg.z + bb.z;
    o.w = dw * rs * gg.w + bb.w;
    *(float4*)(out_f + (size_t)row * 256 + lane * 4) = o;
    if (out_b) {
        size_t i = (size_t)row * 256 + lane * 4;
        out_b[i + 0] = __float2bfloat16(o.x);
        out_b[i + 1] = __float2bfloat16(o.y);
        out_b[i + 2] = __float2bfloat16(o.z);
        out_b[i + 3] = __float2bfloat16(o.w);
    }
}

extern "C" void kernel_launch(void* const* d_in, const int* in_sizes, int n_in,
                              void* d_out, int out_size, void* d_ws, size_t ws_size,
                              hipStream_t stream) {
    const float* x  = (const float*)d_in[0];
    const float* wq = (const float*)d_in[1];
    const float* wk = (const float*)d_in[2];
    const float* wv = (const float*)d_in[3];
    const float* wu = (const float*)d_in[4];
    const float* bu = (const float*)d_in[5];
    const float* w1 = (const float*)d_in[6];
    const float* b1 = (const float*)d_in[7];
    const float* w2 = (const float*)d_in[8];
    const float* b2 = (const float*)d_in[9];
    const float* g1 = (const float*)d_in[10];
    const float* be1 = (const float*)d_in[11];
    const float* g2 = (const float*)d_in[12];
    const float* be2 = (const float*)d_in[13];

    char* p = (char*)d_ws;
    auto alloc = [&](size_t bytes) { char* r = p; p += bytes; return r; };
    __hip_bfloat16* xb    = (__hip_bfloat16*)alloc((size_t)MM * KK * 2);
    __hip_bfloat16* wqkvT = (__hip_bfloat16*)alloc((size_t)NQKV * KK * 2);
    __hip_bfloat16* wuT   = (__hip_bfloat16*)alloc((size_t)KK * 2048 * 2);
    __hip_bfloat16* w1T   = (__hip_bfloat16*)alloc((size_t)1024 * KK * 2);
    __hip_bfloat16* w2T   = (__hip_bfloat16*)alloc((size_t)KK * 1024 * 2);
    __hip_bfloat16* qk    = (__hip_bfloat16*)alloc((size_t)MM * QKS * 2);
    __hip_bfloat16* vt    = (__hip_bfloat16*)alloc((size_t)32 * KK * TT * 2);
    __hip_bfloat16* attn  = (__hip_bfloat16*)alloc((size_t)MM * 2048 * 2);
    float*          y1    = (float*)alloc((size_t)MM * KK * 4);
    float*          x1    = (float*)alloc((size_t)MM * KK * 4);
    __hip_bfloat16* x1b   = (__hip_bfloat16*)alloc((size_t)MM * KK * 2);
    __hip_bfloat16* hid   = (__hip_bfloat16*)alloc((size_t)MM * 1024 * 2);
    float*          y2    = (float*)alloc((size_t)MM * KK * 4);

    // 1. fused prep (cvt + 6 transposes)
    prep_k<<<4608, 256, 0, stream>>>(x, xb, wq, wk, wv, wu, w1, w2,
                                     wqkvT, wuT, w1T, w2T);

    // 2. QKV projection; q/k scale 0.25*sqrt(log2 e); V fused-transposed into vt
    gemm_k<0, 128><<<dim3(NQKV / 128, MM / 128), 256, 0, stream>>>(
        xb, wqkvT, MM, NQKV, 256, nullptr, nullptr, qk, 0.3002806f, vt);

    // 3. flash attention
    attn_k<<<dim3(256), 512, 0, stream>>>(qk, vt, attn);

    // 4. attn-out proj + residual -> y1 (f32); LN1 -> x1 + x1b
    gemm_k<1, 64><<<dim3(4, MM / 128), 256, 0, stream>>>(
        attn, wuT, MM, 256, 2048, bu, x, y1, 1.0f, nullptr);
    layernorm_k<<<MM / 4, 256, 0, stream>>>(y1, g1, be1, x1, x1b);

    // 5. FFN1: relu(x1b @ w1 + b1) -> hid (bf16)
    gemm_k<2, 128><<<dim3(8, MM / 128), 256, 0, stream>>>(
        x1b, w1T, MM, 1024, 256, b1, nullptr, hid, 1.0f, nullptr);

    // 6. FFN2 + residual -> y2; LN2 -> d_out
    gemm_k<1, 64><<<dim3(4, MM / 128), 256, 0, stream>>>(
        hid, w2T, MM, 256, 1024, b2, x1, y2, 1.0f, nullptr);
    layernorm_k<<<MM / 4, 256, 0, stream>>>(y2, g2, be2, (float*)d_out, nullptr);
}

// Round 17
// 233.073 us; speedup vs baseline: 1.2248x; 1.0318x over previous
//
#include <hip/hip_runtime.h>
#include <hip/hip_bf16.h>

#define TT 2048
#define BB 4
#define HH 8
#define KK 256
#define MM (BB*TT)      // 8192 tokens
#define NQKV 6144
#define QKS 4096        // packed Q|K row stride

typedef __attribute__((ext_vector_type(8))) short bf16x8;
typedef __attribute__((ext_vector_type(4))) float f32x4;

__device__ __forceinline__ void gld_lds16(const void* g, void* lds) {
    __builtin_amdgcn_global_load_lds(
        (const __attribute__((address_space(1))) unsigned int*)g,
        (__attribute__((address_space(3))) unsigned int*)lds, 16, 0, 0);
}

// ---------------- fused prep: x->bf16 + 6 weight transpose-converts ----------------
__global__ __launch_bounds__(256) void prep_k(
    const float* __restrict__ x, __hip_bfloat16* __restrict__ xb,
    const float* __restrict__ wq, const float* __restrict__ wk,
    const float* __restrict__ wv, const float* __restrict__ wu,
    const float* __restrict__ w1, const float* __restrict__ w2,
    __hip_bfloat16* __restrict__ wqkvT, __hip_bfloat16* __restrict__ wuT,
    __hip_bfloat16* __restrict__ w1T, __hip_bfloat16* __restrict__ w2T) {
    __shared__ float tile[32][33];
    int bid = blockIdx.x, tid = threadIdx.x;
    if (bid < 2048) {
        int i = (bid * 256 + tid) * 4;
        float4 v = *(const float4*)(x + i);
        xb[i + 0] = __float2bfloat16(v.x);
        xb[i + 1] = __float2bfloat16(v.y);
        xb[i + 2] = __float2bfloat16(v.z);
        xb[i + 3] = __float2bfloat16(v.w);
        return;
    }
    int t = bid - 2048;
    const float* in; __hip_bfloat16* out; int R, C, cx, ry;
    if (t < 1536) {                         // wq / wk / wv: 256 x 2048
        int j = t >> 9, u = t & 511;
        in = (j == 0) ? wq : (j == 1 ? wk : wv);
        out = wqkvT + (size_t)j * 2048 * 256;
        R = 256; C = 2048; cx = u & 63; ry = u >> 6;
    } else if (t < 2048) {                  // wu: 2048 x 256
        int u = t - 1536; in = wu; out = wuT; R = 2048; C = 256; cx = u & 7; ry = u >> 3;
    } else if (t < 2304) {                  // w1: 256 x 1024
        int u = t - 2048; in = w1; out = w1T; R = 256; C = 1024; cx = u & 31; ry = u >> 5;
    } else {                                // w2: 1024 x 256
        int u = t - 2304; in = w2; out = w2T; R = 1024; C = 256; cx = u & 7; ry = u >> 3;
    }
    int c0 = cx * 32, r0 = ry * 32;
    int tx = tid & 31, ty = tid >> 5;
    #pragma unroll
    for (int i = ty; i < 32; i += 8)
        tile[i][tx] = in[(size_t)(r0 + i) * C + c0 + tx];
    __syncthreads();
    #pragma unroll
    for (int i = ty; i < 32; i += 8)
        out[(size_t)(c0 + i) * R + r0 + tx] = __float2bfloat16(tile[tx][i]);
}

// ---------------- GEMM, 2-phase pipelined, BK=64, packed-512B-row LDS ----------------
// BM template param: BM=64 doubles the grid for N=256 GEMMs -> 2 blocks/CU
// (cross-block TLP hides the stage drains; 1 block/CU was occupancy-starved).
// EPI 0: QKV fused epilogue; EPI 1: f32 + bias + res; EPI 2: bf16 relu(+bias).
template<int EPI, int BN, int BM>
__global__ __launch_bounds__(256) void gemm_k(const __hip_bfloat16* __restrict__ A,
                                              const __hip_bfloat16* __restrict__ Bt,
                                              int M, int N, int Kd,
                                              const float* __restrict__ bias,
                                              const float* __restrict__ res,
                                              void* __restrict__ outp, float scale,
                                              __hip_bfloat16* __restrict__ vtp) {
    constexpr int NF = BN / 32;
    constexpr int MF = BM / 32;
    constexpr int APHYS = BM / 4;            // physical 512-B rows in A tile
    constexpr int ASWZM = (APHYS - 1) & 31;
    constexpr int BPHYS = BN / 4;
    constexpr int SWZM = (BPHYS - 1) & 31;
    __shared__ short sA[2][BM * 64];
    __shared__ short sB[2][BN * 64];
    int tid = threadIdx.x, lane = tid & 63, wave = tid >> 6;
    int l15 = lane & 15, g = lane >> 4;
    int m0 = blockIdx.y * BM, n0 = blockIdx.x * BN;
    int wm = (wave >> 1) * (BM / 2), wn = (wave & 1) * (BN / 2);
    f32x4 acc[MF][NF] = {};
    const int NT = Kd >> 6;

    auto STAGE = [&](int kt, int buf) {
        #pragma unroll
        for (int c = 0; c < BM / 32; ++c) {      // A: BM rows x 128 B
            int L = c * 4096 + tid * 16;
            int phys = L >> 9;                   // 0..APHYS-1
            int vp = ((L >> 4) & 31) ^ (phys & ASWZM);
            int row = (vp >> 3) * APHYS + phys;
            gld_lds16(A + (size_t)(m0 + row) * Kd + kt * 64 + (vp & 7) * 8,
                      (char*)sA[buf] + L);
        }
        #pragma unroll
        for (int c = 0; c < BN / 32; ++c) {      // B: BN rows x 128 B
            int L = c * 4096 + tid * 16;
            int phys = L >> 9;                   // 0..BPHYS-1
            int vp = ((L >> 4) & 31) ^ (phys & SWZM);
            int row = (vp >> 3) * BPHYS + phys;
            gld_lds16(Bt + (size_t)(n0 + row) * Kd + kt * 64 + (vp & 7) * 8,
                      (char*)sB[buf] + L);
        }
    };

    STAGE(0, 0);
    asm volatile("s_waitcnt vmcnt(0)" ::: "memory");
    __syncthreads();
    int cur = 0;
    for (int kt = 0; kt < NT; ++kt) {
        if (kt + 1 < NT) STAGE(kt + 1, cur ^ 1);   // issue next tile early
        #pragma unroll
        for (int kk = 0; kk < 2; ++kk) {
            bf16x8 af[MF], bfr[NF];
            #pragma unroll
            for (int mf = 0; mf < MF; ++mf) {
                int R = wm + mf * 16 + l15;
                int v = ((R / APHYS) * 8 + (kk << 2) + g) ^ (R & ASWZM);
                af[mf] = *(const bf16x8*)((char*)sA[cur] + ((R % APHYS) << 9) + (v << 4));
            }
            #pragma unroll
            for (int nf = 0; nf < NF; ++nf) {
                int R = wn + nf * 16 + l15;
                int v = ((R / BPHYS) * 8 + (kk << 2) + g) ^ (R & SWZM);
                bfr[nf] = *(const bf16x8*)((char*)sB[cur] + ((R % BPHYS) << 9) + (v << 4));
            }
            #pragma unroll
            for (int mf = 0; mf < MF; ++mf)
                #pragma unroll
                for (int nf = 0; nf < NF; ++nf)
                    acc[mf][nf] = __builtin_amdgcn_mfma_f32_16x16x32_bf16(af[mf], bfr[nf], acc[mf][nf], 0, 0, 0);
        }
        asm volatile("s_waitcnt vmcnt(0)" ::: "memory");   // next tile landed
        __syncthreads();                                    // all waves done with cur
        cur ^= 1;
    }

    #pragma unroll
    for (int mf = 0; mf < MF; ++mf) {
        int rowb = m0 + wm + mf * 16 + g * 4;
        #pragma unroll
        for (int nf = 0; nf < NF; ++nf) {
            int col = n0 + wn + nf * 16 + l15;
            if (EPI == 0) {
                if (col < 4096) {
                    #pragma unroll
                    for (int r = 0; r < 4; ++r)
                        ((__hip_bfloat16*)outp)[(size_t)(rowb + r) * QKS + col] =
                            __float2bfloat16(acc[mf][nf][r] * scale);
                } else {
                    int hv = col - 4096, h = hv >> 8, d = hv & 255;
                    int b = rowb >> 11, t = rowb & 2047;
                    ushort4 w;
                    w.x = __bfloat16_as_ushort(__float2bfloat16(acc[mf][nf][0]));
                    w.y = __bfloat16_as_ushort(__float2bfloat16(acc[mf][nf][1]));
                    w.z = __bfloat16_as_ushort(__float2bfloat16(acc[mf][nf][2]));
                    w.w = __bfloat16_as_ushort(__float2bfloat16(acc[mf][nf][3]));
                    *(ushort4*)(vtp + ((size_t)((b * 8 + h) * 256 + d)) * TT + t) = w;
                }
            } else {
                #pragma unroll
                for (int r = 0; r < 4; ++r) {
                    float v = acc[mf][nf][r];
                    size_t idx = (size_t)(rowb + r) * N + col;
                    if (EPI == 1) {
                        ((float*)outp)[idx] = v + bias[col] + res[idx];
                    } else {
                        v += bias[col];
                        ((__hip_bfloat16*)outp)[idx] = __float2bfloat16(v > 0.0f ? v : 0.0f);
                    }
                }
            }
        }
    }
}

// ---------------- flash attention: 8 waves x 16 q-rows, dbuf LDS, swapped-QK softmax ----
// (round-16 proven: K full 5-bit swizzle, V cheap round-8 layout; 121 us)
__global__ __launch_bounds__(512, 2) void attn_k(const __hip_bfloat16* __restrict__ QK,
                                                 const __hip_bfloat16* __restrict__ VT,
                                                 __hip_bfloat16* __restrict__ O) {
    __shared__ char Kl[2][32768];
    __shared__ char Vl[2][32768];
    __shared__ char Pl[8][2048];     // per-wave P: [16 q][64 s] bf16, XOR-swizzled
    int tid = threadIdx.x, lane = tid & 63, wave = tid >> 6;
    int id = blockIdx.x;
    int xcd = id & 7, w = id >> 3;            // w: 0..31
    int bh = xcd * 4 + (w >> 3);
    int jtp = w & 7;
    int b = bh >> 3, h = bh & 7;
    const __hip_bfloat16* Qb = QK + (size_t)b * TT * QKS + h * KK;
    const __hip_bfloat16* Kb = Qb + 2048;
    const __hip_bfloat16* Vtb = VT + (size_t)bh * KK * TT;

    int l15 = lane & 15, g = lane >> 4;
    int koff = g * 8;            // elements
    int koffB = g * 16;          // bytes
    int pswz = (l15 & 7) << 4;   // P-tile swizzle for this lane's q-row

    auto STAGE = [&](int s0, int buf) {
        #pragma unroll
        for (int rd = 0; rd < 4; ++rd) {        // K: 64 rows x 512 B, full 5-bit XOR
            int L = rd * 8192 + tid * 16;
            int row = L >> 9;
            int cb = (L & 511) ^ ((row & 31) << 4);
            gld_lds16((const char*)(Kb + (size_t)(s0 + row) * QKS) + cb,
                      Kl[buf] + rd * 8192 + wave * 1024);
        }
        #pragma unroll
        for (int rd = 0; rd < 4; ++rd) {        // V: 256 rows x 128 B (cheap addressing)
            int L = rd * 8192 + tid * 16;
            int row = L >> 7;
            int cb = (L & 127) ^ ((row & 7) << 4);
            gld_lds16((const char*)(Vtb + (size_t)row * TT + s0) + cb,
                      Vl[buf] + rd * 8192 + wave * 1024);
        }
    };

    #pragma unroll 1
    for (int half = 0; half < 2; ++half) {
        int jt = (half == 0) ? jtp : 15 - jtp;
        int q0 = jt * 128;
        int rowbase = q0 + wave * 16;
        bf16x8 qf[8];
        #pragma unroll
        for (int kk = 0; kk < 8; ++kk)
            qf[kk] = *(const bf16x8*)(Qb + (size_t)(rowbase + l15) * QKS + kk * 32 + koff);

        f32x4 Oa[16] = {};
        float mrow = -__builtin_inff();
        float lrow = 0.f;

        STAGE(0, 0);
        asm volatile("s_waitcnt vmcnt(0)" ::: "memory");
        __syncthreads();
        int cur = 0;
        const int niter = 2 * jt + 2;

        #pragma unroll 1
        for (int i = 0; i < niter; ++i) {
            int s0 = i * 64;
            if (i + 1 < niter) STAGE(s0 + 64, cur ^ 1);   // prefetch into other buffer

            if (s0 <= rowbase + 15) {                     // wave has unmasked rows
                // ---- QK^T swapped: S = K-tile x Q-frag (lane col = q = l15)
                f32x4 S[4] = {};
                __builtin_amdgcn_s_setprio(1);
                #pragma unroll
                for (int nf = 0; nf < 4; ++nf) {
                    int r = nf * 16 + l15;
                    int swz = (r & 31) << 4;
                    #pragma unroll
                    for (int kk = 0; kk < 8; ++kk) {
                        bf16x8 kf = *(const bf16x8*)(Kl[cur] + r * 512 + ((kk * 64 + koffB) ^ swz));
                        S[nf] = __builtin_amdgcn_mfma_f32_16x16x32_bf16(kf, qf[kk], S[nf], 0, 0, 0);
                    }
                }
                __builtin_amdgcn_s_setprio(0);
                if (s0 + 63 > rowbase) {                  // causal: S row = s, col = q
                    int qg = rowbase + l15;
                    #pragma unroll
                    for (int nf = 0; nf < 4; ++nf)
                        #pragma unroll
                        for (int r = 0; r < 4; ++r) {
                            int sg = s0 + nf * 16 + g * 4 + r;
                            if (sg > qg) S[nf][r] = -__builtin_inff();
                        }
                }
                // ---- softmax (exp2 domain), stats lane-local in l15
                float mx = S[0][0];
                #pragma unroll
                for (int nf = 0; nf < 4; ++nf)
                    #pragma unroll
                    for (int r = 0; r < 4; ++r) mx = fmaxf(mx, S[nf][r]);
                mx = fmaxf(mx, __shfl_xor(mx, 16));
                mx = fmaxf(mx, __shfl_xor(mx, 32));
                if (__any(mx > mrow + 8.0f)) {            // defer-max rescale
                    float mn = fmaxf(mrow, mx);
                    float alpha = exp2f(mrow - mn);
                    mrow = mn;
                    lrow *= alpha;
                    float al[4];
                    #pragma unroll
                    for (int r = 0; r < 4; ++r) al[r] = __shfl(alpha, (g << 2) + r);
                    #pragma unroll
                    for (int nf2 = 0; nf2 < 16; ++nf2)
                        #pragma unroll
                        for (int r = 0; r < 4; ++r) Oa[nf2][r] *= al[r];
                }
                float ps = 0.f;
                #pragma unroll
                for (int nf = 0; nf < 4; ++nf)
                    #pragma unroll
                    for (int r = 0; r < 4; ++r) {
                        float p = exp2f(S[nf][r] - mrow);
                        S[nf][r] = p; ps += p;
                    }
                ps += __shfl_xor(ps, 16);
                ps += __shfl_xor(ps, 32);
                lrow += ps;
                // ---- P -> LDS [q=l15][s], b64 packed writes, swizzled
                #pragma unroll
                for (int nf = 0; nf < 4; ++nf) {
                    uint2 pk2;
                    pk2.x = (unsigned)__bfloat16_as_ushort(__float2bfloat16(S[nf][0]))
                          | ((unsigned)__bfloat16_as_ushort(__float2bfloat16(S[nf][1])) << 16);
                    pk2.y = (unsigned)__bfloat16_as_ushort(__float2bfloat16(S[nf][2]))
                          | ((unsigned)__bfloat16_as_ushort(__float2bfloat16(S[nf][3])) << 16);
                    *(uint2*)(Pl[wave] + l15 * 128 + ((nf * 32 + g * 8) ^ pswz)) = pk2;
                }
                // ---- PV: O += P @ V
                bf16x8 pa[2];
                #pragma unroll
                for (int kk2 = 0; kk2 < 2; ++kk2)
                    pa[kk2] = *(const bf16x8*)(Pl[wave] + l15 * 128 + ((kk2 * 64 + koffB) ^ pswz));
                __builtin_amdgcn_s_setprio(1);
                #pragma unroll
                for (int nf2 = 0; nf2 < 16; ++nf2) {
                    int r = nf2 * 16 + l15;
                    int swz = (r & 7) << 4;
                    #pragma unroll
                    for (int kk2 = 0; kk2 < 2; ++kk2) {
                        bf16x8 vb = *(const bf16x8*)(Vl[cur] + r * 128 + ((kk2 * 64 + koffB) ^ swz));
                        Oa[nf2] = __builtin_amdgcn_mfma_f32_16x16x32_bf16(pa[kk2], vb, Oa[nf2], 0, 0, 0);
                    }
                }
                __builtin_amdgcn_s_setprio(0);
            }
            asm volatile("s_waitcnt vmcnt(0)" ::: "memory");   // own prefetch landed
            __syncthreads();                                    // all waves done + staged
            cur ^= 1;
        }
        // ---- write this q-tile's output
        float rcp_ = 1.0f / lrow;
        float rc[4];
        #pragma unroll
        for (int r = 0; r < 4; ++r) rc[r] = __shfl(rcp_, (g << 2) + r);
        #pragma unroll
        for (int nf2 = 0; nf2 < 16; ++nf2) {
            int col = nf2 * 16 + l15;
            #pragma unroll
            for (int r = 0; r < 4; ++r) {
                int t = rowbase + g * 4 + r;
                O[((size_t)b * TT + t) * 2048 + h * KK + col] = __float2bfloat16(Oa[nf2][r] * rc[r]);
            }
        }
    }
}

// ---------------- row LayerNorm over K=256, 4 rows/block ----------------
__global__ __launch_bounds__(256) void layernorm_k(const float* __restrict__ y,
                                                   const float* __restrict__ g,
                                                   const float* __restrict__ be,
                                                   float* __restrict__ out_f,
                                                   __hip_bfloat16* __restrict__ out_b) {
    int row = blockIdx.x * 4 + (threadIdx.x >> 6);
    int lane = threadIdx.x & 63;
    float4 v = *(const float4*)(y + (size_t)row * 256 + lane * 4);
    float s = v.x + v.y + v.z + v.w;
    #pragma unroll
    for (int d = 1; d < 64; d <<= 1) s += __shfl_xor(s, d);
    float mu = s * (1.0f / 256.0f);
    float dx = v.x - mu, dy = v.y - mu, dz = v.z - mu, dw = v.w - mu;
    float q = dx * dx + dy * dy + dz * dz + dw * dw;
    #pragma unroll
    for (int d = 1; d < 64; d <<= 1) q += __shfl_xor(q, d);
    float rs = rsqrtf(q * (1.0f / 256.0f) + 1e-5f);
    float4 gg = *(const float4*)(g + lane * 4);
    float4 bb = *(const float4*)(be + lane * 4);
    float4 o;
    o.x = dx * rs * gg.x + bb.x;
    o.y = dy * rs * gg.y + bb.y;
    o.z = dz * rs * gg.z + bb.z;
    o.w = dw * rs * gg.w + bb.w;
    *(float4*)(out_f + (size_t)row * 256 + lane * 4) = o;
    if (out_b) {
        size_t i = (size_t)row * 256 + lane * 4;
        out_b[i + 0] = __float2bfloat16(o.x);
        out_b[i + 1] = __float2bfloat16(o.y);
        out_b[i + 2] = __float2bfloat16(o.z);
        out_b[i + 3] = __float2bfloat16(o.w);
    }
}

extern "C" void kernel_launch(void* const* d_in, const int* in_sizes, int n_in,
                              void* d_out, int out_size, void* d_ws, size_t ws_size,
                              hipStream_t stream) {
    const float* x  = (const float*)d_in[0];
    const float* wq = (const float*)d_in[1];
    const float* wk = (const float*)d_in[2];
    const float* wv = (const float*)d_in[3];
    const float* wu = (const float*)d_in[4];
    const float* bu = (const float*)d_in[5];
    const float* w1 = (const float*)d_in[6];
    const float* b1 = (const float*)d_in[7];
    const float* w2 = (const float*)d_in[8];
    const float* b2 = (const float*)d_in[9];
    const float* g1 = (const float*)d_in[10];
    const float* be1 = (const float*)d_in[11];
    const float* g2 = (const float*)d_in[12];
    const float* be2 = (const float*)d_in[13];

    char* p = (char*)d_ws;
    auto alloc = [&](size_t bytes) { char* r = p; p += bytes; return r; };
    __hip_bfloat16* xb    = (__hip_bfloat16*)alloc((size_t)MM * KK * 2);
    __hip_bfloat16* wqkvT = (__hip_bfloat16*)alloc((size_t)NQKV * KK * 2);
    __hip_bfloat16* wuT   = (__hip_bfloat16*)alloc((size_t)KK * 2048 * 2);
    __hip_bfloat16* w1T   = (__hip_bfloat16*)alloc((size_t)1024 * KK * 2);
    __hip_bfloat16* w2T   = (__hip_bfloat16*)alloc((size_t)KK * 1024 * 2);
    __hip_bfloat16* qk    = (__hip_bfloat16*)alloc((size_t)MM * QKS * 2);
    __hip_bfloat16* vt    = (__hip_bfloat16*)alloc((size_t)32 * KK * TT * 2);
    __hip_bfloat16* attn  = (__hip_bfloat16*)alloc((size_t)MM * 2048 * 2);
    float*          y1    = (float*)alloc((size_t)MM * KK * 4);
    float*          x1    = (float*)alloc((size_t)MM * KK * 4);
    __hip_bfloat16* x1b   = (__hip_bfloat16*)alloc((size_t)MM * KK * 2);
    __hip_bfloat16* hid   = (__hip_bfloat16*)alloc((size_t)MM * 1024 * 2);
    float*          y2    = (float*)alloc((size_t)MM * KK * 4);

    // 1. fused prep (cvt + 6 transposes)
    prep_k<<<4608, 256, 0, stream>>>(x, xb, wq, wk, wv, wu, w1, w2,
                                     wqkvT, wuT, w1T, w2T);

    // 2. QKV projection; q/k scale 0.25*sqrt(log2 e); V fused-transposed into vt
    gemm_k<0, 128, 128><<<dim3(NQKV / 128, MM / 128), 256, 0, stream>>>(
        xb, wqkvT, MM, NQKV, 256, nullptr, nullptr, qk, 0.3002806f, vt);

    // 3. flash attention
    attn_k<<<dim3(256), 512, 0, stream>>>(qk, vt, attn);

    // 4. attn-out proj + residual -> y1 (f32); LN1 -> x1 + x1b   (BM=64: 512 blocks)
    gemm_k<1, 64, 64><<<dim3(4, MM / 64), 256, 0, stream>>>(
        attn, wuT, MM, 256, 2048, bu, x, y1, 1.0f, nullptr);
    layernorm_k<<<MM / 4, 256, 0, stream>>>(y1, g1, be1, x1, x1b);

    // 5. FFN1: relu(x1b @ w1 + b1) -> hid (bf16)
    gemm_k<2, 128, 128><<<dim3(8, MM / 128), 256, 0, stream>>>(
        x1b, w1T, MM, 1024, 256, b1, nullptr, hid, 1.0f, nullptr);

    // 6. FFN2 + residual -> y2; LN2 -> d_out   (BM=64: 512 blocks)
    gemm_k<1, 64, 64><<<dim3(4, MM / 64), 256, 0, stream>>>(
        hid, w2T, MM, 256, 1024, b2, x1, y2, 1.0f, nullptr);
    layernorm_k<<<MM / 4, 256, 0, stream>>>(y2, g2, be2, (float*)d_out, nullptr);
}

// Round 18
// 225.255 us; speedup vs baseline: 1.2673x; 1.0347x over previous
//
#include <hip/hip_runtime.h>
#include <hip/hip_bf16.h>

#define TT 2048
#define BB 4
#define HH 8
#define KK 256
#define MM (BB*TT)      // 8192 tokens
#define NQKV 6144
#define QKS 4096        // packed Q|K row stride

typedef __attribute__((ext_vector_type(8))) short bf16x8;
typedef __attribute__((ext_vector_type(4))) float f32x4;

__device__ __forceinline__ void gld_lds16(const void* g, void* lds) {
    __builtin_amdgcn_global_load_lds(
        (const __attribute__((address_space(1))) unsigned int*)g,
        (__attribute__((address_space(3))) unsigned int*)lds, 16, 0, 0);
}

// ---------------- fused prep: x->bf16 + 6 weight transpose-converts ----------------
__global__ __launch_bounds__(256) void prep_k(
    const float* __restrict__ x, __hip_bfloat16* __restrict__ xb,
    const float* __restrict__ wq, const float* __restrict__ wk,
    const float* __restrict__ wv, const float* __restrict__ wu,
    const float* __restrict__ w1, const float* __restrict__ w2,
    __hip_bfloat16* __restrict__ wqkvT, __hip_bfloat16* __restrict__ wuT,
    __hip_bfloat16* __restrict__ w1T, __hip_bfloat16* __restrict__ w2T) {
    __shared__ float tile[32][33];
    int bid = blockIdx.x, tid = threadIdx.x;
    if (bid < 2048) {
        int i = (bid * 256 + tid) * 4;
        float4 v = *(const float4*)(x + i);
        xb[i + 0] = __float2bfloat16(v.x);
        xb[i + 1] = __float2bfloat16(v.y);
        xb[i + 2] = __float2bfloat16(v.z);
        xb[i + 3] = __float2bfloat16(v.w);
        return;
    }
    int t = bid - 2048;
    const float* in; __hip_bfloat16* out; int R, C, cx, ry;
    if (t < 1536) {                         // wq / wk / wv: 256 x 2048
        int j = t >> 9, u = t & 511;
        in = (j == 0) ? wq : (j == 1 ? wk : wv);
        out = wqkvT + (size_t)j * 2048 * 256;
        R = 256; C = 2048; cx = u & 63; ry = u >> 6;
    } else if (t < 2048) {                  // wu: 2048 x 256
        int u = t - 1536; in = wu; out = wuT; R = 2048; C = 256; cx = u & 7; ry = u >> 3;
    } else if (t < 2304) {                  // w1: 256 x 1024
        int u = t - 2048; in = w1; out = w1T; R = 256; C = 1024; cx = u & 31; ry = u >> 5;
    } else {                                // w2: 1024 x 256
        int u = t - 2304; in = w2; out = w2T; R = 1024; C = 256; cx = u & 7; ry = u >> 3;
    }
    int c0 = cx * 32, r0 = ry * 32;
    int tx = tid & 31, ty = tid >> 5;
    #pragma unroll
    for (int i = ty; i < 32; i += 8)
        tile[i][tx] = in[(size_t)(r0 + i) * C + c0 + tx];
    __syncthreads();
    #pragma unroll
    for (int i = ty; i < 32; i += 8)
        out[(size_t)(c0 + i) * R + r0 + tx] = __float2bfloat16(tile[tx][i]);
}

// ---------------- GEMM, 2-phase pipelined, BK=64, packed-512B-row LDS ----------------
// BM/BN templated. BM=32/BN=64 for K-deep N=256 GEMMs: 1024 blocks, 24 KB LDS
// -> 3+ blocks/CU (occupancy ladder: more TLP hides the per-K-step stage drains).
// EPI 0: QKV fused epilogue; EPI 1: f32 + bias + res; EPI 2: bf16 relu(+bias).
template<int EPI, int BN, int BM>
__global__ __launch_bounds__(256) void gemm_k(const __hip_bfloat16* __restrict__ A,
                                              const __hip_bfloat16* __restrict__ Bt,
                                              int M, int N, int Kd,
                                              const float* __restrict__ bias,
                                              const float* __restrict__ res,
                                              void* __restrict__ outp, float scale,
                                              __hip_bfloat16* __restrict__ vtp) {
    constexpr int NF = BN / 32;
    constexpr int MF = (BM + 31) / 32;
    constexpr int APHYS = BM / 4;            // physical 512-B rows in A tile
    constexpr int ASWZM = (APHYS - 1) & 31;
    constexpr int BPHYS = BN / 4;
    constexpr int SWZM = (BPHYS - 1) & 31;
    __shared__ short sA[2][BM * 64];
    __shared__ short sB[2][BN * 64];
    int tid = threadIdx.x, lane = tid & 63, wave = tid >> 6;
    int l15 = lane & 15, g = lane >> 4;
    int m0 = blockIdx.y * BM, n0 = blockIdx.x * BN;
    int wm = (wave >> 1) * (BM / 2), wn = (wave & 1) * (BN / 2);
    f32x4 acc[MF][NF] = {};
    const int NT = Kd >> 6;

    auto STAGE = [&](int kt, int buf) {
        #pragma unroll
        for (int c = 0; c < BM / 32; ++c) {      // A: BM rows x 128 B
            int L = c * 4096 + tid * 16;
            int phys = L >> 9;                   // 0..APHYS-1
            int vp = ((L >> 4) & 31) ^ (phys & ASWZM);
            int row = (vp >> 3) * APHYS + phys;
            gld_lds16(A + (size_t)(m0 + row) * Kd + kt * 64 + (vp & 7) * 8,
                      (char*)sA[buf] + L);
        }
        #pragma unroll
        for (int c = 0; c < BN / 32; ++c) {      // B: BN rows x 128 B
            int L = c * 4096 + tid * 16;
            int phys = L >> 9;                   // 0..BPHYS-1
            int vp = ((L >> 4) & 31) ^ (phys & SWZM);
            int row = (vp >> 3) * BPHYS + phys;
            gld_lds16(Bt + (size_t)(n0 + row) * Kd + kt * 64 + (vp & 7) * 8,
                      (char*)sB[buf] + L);
        }
    };

    STAGE(0, 0);
    asm volatile("s_waitcnt vmcnt(0)" ::: "memory");
    __syncthreads();
    int cur = 0;
    for (int kt = 0; kt < NT; ++kt) {
        if (kt + 1 < NT) STAGE(kt + 1, cur ^ 1);   // issue next tile early
        #pragma unroll
        for (int kk = 0; kk < 2; ++kk) {
            bf16x8 af[MF], bfr[NF];
            #pragma unroll
            for (int mf = 0; mf < MF; ++mf) {
                int R = wm + mf * 16 + l15;
                int v = ((R / APHYS) * 8 + (kk << 2) + g) ^ (R & ASWZM);
                af[mf] = *(const bf16x8*)((char*)sA[cur] + ((R % APHYS) << 9) + (v << 4));
            }
            #pragma unroll
            for (int nf = 0; nf < NF; ++nf) {
                int R = wn + nf * 16 + l15;
                int v = ((R / BPHYS) * 8 + (kk << 2) + g) ^ (R & SWZM);
                bfr[nf] = *(const bf16x8*)((char*)sB[cur] + ((R % BPHYS) << 9) + (v << 4));
            }
            #pragma unroll
            for (int mf = 0; mf < MF; ++mf)
                #pragma unroll
                for (int nf = 0; nf < NF; ++nf)
                    acc[mf][nf] = __builtin_amdgcn_mfma_f32_16x16x32_bf16(af[mf], bfr[nf], acc[mf][nf], 0, 0, 0);
        }
        asm volatile("s_waitcnt vmcnt(0)" ::: "memory");   // next tile landed
        __syncthreads();                                    // all waves done with cur
        cur ^= 1;
    }

    #pragma unroll
    for (int mf = 0; mf < MF; ++mf) {
        int rowb = m0 + wm + mf * 16 + g * 4;
        #pragma unroll
        for (int nf = 0; nf < NF; ++nf) {
            int col = n0 + wn + nf * 16 + l15;
            if (EPI == 0) {
                if (col < 4096) {
                    #pragma unroll
                    for (int r = 0; r < 4; ++r)
                        ((__hip_bfloat16*)outp)[(size_t)(rowb + r) * QKS + col] =
                            __float2bfloat16(acc[mf][nf][r] * scale);
                } else {
                    int hv = col - 4096, h = hv >> 8, d = hv & 255;
                    int b = rowb >> 11, t = rowb & 2047;
                    ushort4 w;
                    w.x = __bfloat16_as_ushort(__float2bfloat16(acc[mf][nf][0]));
                    w.y = __bfloat16_as_ushort(__float2bfloat16(acc[mf][nf][1]));
                    w.z = __bfloat16_as_ushort(__float2bfloat16(acc[mf][nf][2]));
                    w.w = __bfloat16_as_ushort(__float2bfloat16(acc[mf][nf][3]));
                    *(ushort4*)(vtp + ((size_t)((b * 8 + h) * 256 + d)) * TT + t) = w;
                }
            } else {
                #pragma unroll
                for (int r = 0; r < 4; ++r) {
                    float v = acc[mf][nf][r];
                    size_t idx = (size_t)(rowb + r) * N + col;
                    if (EPI == 1) {
                        ((float*)outp)[idx] = v + bias[col] + res[idx];
                    } else {
                        v += bias[col];
                        ((__hip_bfloat16*)outp)[idx] = __float2bfloat16(v > 0.0f ? v : 0.0f);
                    }
                }
            }
        }
    }
}

// ---------------- flash attention: 8 waves x 16 q-rows, dbuf LDS, swapped-QK softmax ----
// Round-16 structure; setprio REMOVED (barrier-locked 8-wave schedule = the
// regime where setprio hurt GEMM, m190); diagonal fully-masked nf-subtiles skip
// their 8 MFMAs + kf reads (wave-uniform branch; mask path still zeroes them).
__global__ __launch_bounds__(512, 2) void attn_k(const __hip_bfloat16* __restrict__ QK,
                                                 const __hip_bfloat16* __restrict__ VT,
                                                 __hip_bfloat16* __restrict__ O) {
    __shared__ char Kl[2][32768];
    __shared__ char Vl[2][32768];
    __shared__ char Pl[8][2048];     // per-wave P: [16 q][64 s] bf16, XOR-swizzled
    int tid = threadIdx.x, lane = tid & 63, wave = tid >> 6;
    int id = blockIdx.x;
    int xcd = id & 7, w = id >> 3;            // w: 0..31
    int bh = xcd * 4 + (w >> 3);
    int jtp = w & 7;
    int b = bh >> 3, h = bh & 7;
    const __hip_bfloat16* Qb = QK + (size_t)b * TT * QKS + h * KK;
    const __hip_bfloat16* Kb = Qb + 2048;
    const __hip_bfloat16* Vtb = VT + (size_t)bh * KK * TT;

    int l15 = lane & 15, g = lane >> 4;
    int koff = g * 8;            // elements
    int koffB = g * 16;          // bytes
    int pswz = (l15 & 7) << 4;   // P-tile swizzle for this lane's q-row

    auto STAGE = [&](int s0, int buf) {
        #pragma unroll
        for (int rd = 0; rd < 4; ++rd) {        // K: 64 rows x 512 B, full 5-bit XOR
            int L = rd * 8192 + tid * 16;
            int row = L >> 9;
            int cb = (L & 511) ^ ((row & 31) << 4);
            gld_lds16((const char*)(Kb + (size_t)(s0 + row) * QKS) + cb,
                      Kl[buf] + rd * 8192 + wave * 1024);
        }
        #pragma unroll
        for (int rd = 0; rd < 4; ++rd) {        // V: 256 rows x 128 B (cheap addressing)
            int L = rd * 8192 + tid * 16;
            int row = L >> 7;
            int cb = (L & 127) ^ ((row & 7) << 4);
            gld_lds16((const char*)(Vtb + (size_t)row * TT + s0) + cb,
                      Vl[buf] + rd * 8192 + wave * 1024);
        }
    };

    #pragma unroll 1
    for (int half = 0; half < 2; ++half) {
        int jt = (half == 0) ? jtp : 15 - jtp;
        int q0 = jt * 128;
        int rowbase = q0 + wave * 16;
        bf16x8 qf[8];
        #pragma unroll
        for (int kk = 0; kk < 8; ++kk)
            qf[kk] = *(const bf16x8*)(Qb + (size_t)(rowbase + l15) * QKS + kk * 32 + koff);

        f32x4 Oa[16] = {};
        float mrow = -__builtin_inff();
        float lrow = 0.f;

        STAGE(0, 0);
        asm volatile("s_waitcnt vmcnt(0)" ::: "memory");
        __syncthreads();
        int cur = 0;
        const int niter = 2 * jt + 2;

        #pragma unroll 1
        for (int i = 0; i < niter; ++i) {
            int s0 = i * 64;
            if (i + 1 < niter) STAGE(s0 + 64, cur ^ 1);   // prefetch into other buffer

            if (s0 <= rowbase + 15) {                     // wave has unmasked rows
                // ---- QK^T swapped: S = K-tile x Q-frag (lane col = q = l15)
                f32x4 S[4] = {};
                #pragma unroll
                for (int nf = 0; nf < 4; ++nf) {
                    if (s0 + nf * 16 <= rowbase + 15) {   // skip fully-masked subtiles
                        int r = nf * 16 + l15;
                        int swz = (r & 31) << 4;
                        #pragma unroll
                        for (int kk = 0; kk < 8; ++kk) {
                            bf16x8 kf = *(const bf16x8*)(Kl[cur] + r * 512 + ((kk * 64 + koffB) ^ swz));
                            S[nf] = __builtin_amdgcn_mfma_f32_16x16x32_bf16(kf, qf[kk], S[nf], 0, 0, 0);
                        }
                    }
                }
                if (s0 + 63 > rowbase) {                  // causal: S row = s, col = q
                    int qg = rowbase + l15;
                    #pragma unroll
                    for (int nf = 0; nf < 4; ++nf)
                        #pragma unroll
                        for (int r = 0; r < 4; ++r) {
                            int sg = s0 + nf * 16 + g * 4 + r;
                            if (sg > qg) S[nf][r] = -__builtin_inff();
                        }
                }
                // ---- softmax (exp2 domain), stats lane-local in l15
                float mx = S[0][0];
                #pragma unroll
                for (int nf = 0; nf < 4; ++nf)
                    #pragma unroll
                    for (int r = 0; r < 4; ++r) mx = fmaxf(mx, S[nf][r]);
                mx = fmaxf(mx, __shfl_xor(mx, 16));
                mx = fmaxf(mx, __shfl_xor(mx, 32));
                if (__any(mx > mrow + 8.0f)) {            // defer-max rescale
                    float mn = fmaxf(mrow, mx);
                    float alpha = exp2f(mrow - mn);
                    mrow = mn;
                    lrow *= alpha;
                    float al[4];
                    #pragma unroll
                    for (int r = 0; r < 4; ++r) al[r] = __shfl(alpha, (g << 2) + r);
                    #pragma unroll
                    for (int nf2 = 0; nf2 < 16; ++nf2)
                        #pragma unroll
                        for (int r = 0; r < 4; ++r) Oa[nf2][r] *= al[r];
                }
                float ps = 0.f;
                #pragma unroll
                for (int nf = 0; nf < 4; ++nf)
                    #pragma unroll
                    for (int r = 0; r < 4; ++r) {
                        float p = exp2f(S[nf][r] - mrow);
                        S[nf][r] = p; ps += p;
                    }
                ps += __shfl_xor(ps, 16);
                ps += __shfl_xor(ps, 32);
                lrow += ps;
                // ---- P -> LDS [q=l15][s], b64 packed writes, swizzled
                #pragma unroll
                for (int nf = 0; nf < 4; ++nf) {
                    uint2 pk2;
                    pk2.x = (unsigned)__bfloat16_as_ushort(__float2bfloat16(S[nf][0]))
                          | ((unsigned)__bfloat16_as_ushort(__float2bfloat16(S[nf][1])) << 16);
                    pk2.y = (unsigned)__bfloat16_as_ushort(__float2bfloat16(S[nf][2]))
                          | ((unsigned)__bfloat16_as_ushort(__float2bfloat16(S[nf][3])) << 16);
                    *(uint2*)(Pl[wave] + l15 * 128 + ((nf * 32 + g * 8) ^ pswz)) = pk2;
                }
                // ---- PV: O += P @ V
                bf16x8 pa[2];
                #pragma unroll
                for (int kk2 = 0; kk2 < 2; ++kk2)
                    pa[kk2] = *(const bf16x8*)(Pl[wave] + l15 * 128 + ((kk2 * 64 + koffB) ^ pswz));
                #pragma unroll
                for (int nf2 = 0; nf2 < 16; ++nf2) {
                    int r = nf2 * 16 + l15;
                    int swz = (r & 7) << 4;
                    #pragma unroll
                    for (int kk2 = 0; kk2 < 2; ++kk2) {
                        bf16x8 vb = *(const bf16x8*)(Vl[cur] + r * 128 + ((kk2 * 64 + koffB) ^ swz));
                        Oa[nf2] = __builtin_amdgcn_mfma_f32_16x16x32_bf16(pa[kk2], vb, Oa[nf2], 0, 0, 0);
                    }
                }
            }
            asm volatile("s_waitcnt vmcnt(0)" ::: "memory");   // own prefetch landed
            __syncthreads();                                    // all waves done + staged
            cur ^= 1;
        }
        // ---- write this q-tile's output
        float rcp_ = 1.0f / lrow;
        float rc[4];
        #pragma unroll
        for (int r = 0; r < 4; ++r) rc[r] = __shfl(rcp_, (g << 2) + r);
        #pragma unroll
        for (int nf2 = 0; nf2 < 16; ++nf2) {
            int col = nf2 * 16 + l15;
            #pragma unroll
            for (int r = 0; r < 4; ++r) {
                int t = rowbase + g * 4 + r;
                O[((size_t)b * TT + t) * 2048 + h * KK + col] = __float2bfloat16(Oa[nf2][r] * rc[r]);
            }
        }
    }
}

// ---------------- row LayerNorm over K=256, 4 rows/block ----------------
__global__ __launch_bounds__(256) void layernorm_k(const float* __restrict__ y,
                                                   const float* __restrict__ g,
                                                   const float* __restrict__ be,
                                                   float* __restrict__ out_f,
                                                   __hip_bfloat16* __restrict__ out_b) {
    int row = blockIdx.x * 4 + (threadIdx.x >> 6);
    int lane = threadIdx.x & 63;
    float4 v = *(const float4*)(y + (size_t)row * 256 + lane * 4);
    float s = v.x + v.y + v.z + v.w;
    #pragma unroll
    for (int d = 1; d < 64; d <<= 1) s += __shfl_xor(s, d);
    float mu = s * (1.0f / 256.0f);
    float dx = v.x - mu, dy = v.y - mu, dz = v.z - mu, dw = v.w - mu;
    float q = dx * dx + dy * dy + dz * dz + dw * dw;
    #pragma unroll
    for (int d = 1; d < 64; d <<= 1) q += __shfl_xor(q, d);
    float rs = rsqrtf(q * (1.0f / 256.0f) + 1e-5f);
    float4 gg = *(const float4*)(g + lane * 4);
    float4 bb = *(const float4*)(be + lane * 4);
    float4 o;
    o.x = dx * rs * gg.x + bb.x;
    o.y = dy * rs * gg.y + bb.y;
    o.z = dz * rs * gg.z + bb.z;
    o.w = dw * rs * gg.w + bb.w;
    *(float4*)(out_f + (size_t)row * 256 + lane * 4) = o;
    if (out_b) {
        size_t i = (size_t)row * 256 + lane * 4;
        out_b[i + 0] = __float2bfloat16(o.x);
        out_b[i + 1] = __float2bfloat16(o.y);
        out_b[i + 2] = __float2bfloat16(o.z);
        out_b[i + 3] = __float2bfloat16(o.w);
    }
}

extern "C" void kernel_launch(void* const* d_in, const int* in_sizes, int n_in,
                              void* d_out, int out_size, void* d_ws, size_t ws_size,
                              hipStream_t stream) {
    const float* x  = (const float*)d_in[0];
    const float* wq = (const float*)d_in[1];
    const float* wk = (const float*)d_in[2];
    const float* wv = (const float*)d_in[3];
    const float* wu = (const float*)d_in[4];
    const float* bu = (const float*)d_in[5];
    const float* w1 = (const float*)d_in[6];
    const float* b1 = (const float*)d_in[7];
    const float* w2 = (const float*)d_in[8];
    const float* b2 = (const float*)d_in[9];
    const float* g1 = (const float*)d_in[10];
    const float* be1 = (const float*)d_in[11];
    const float* g2 = (const float*)d_in[12];
    const float* be2 = (const float*)d_in[13];

    char* p = (char*)d_ws;
    auto alloc = [&](size_t bytes) { char* r = p; p += bytes; return r; };
    __hip_bfloat16* xb    = (__hip_bfloat16*)alloc((size_t)MM * KK * 2);
    __hip_bfloat16* wqkvT = (__hip_bfloat16*)alloc((size_t)NQKV * KK * 2);
    __hip_bfloat16* wuT   = (__hip_bfloat16*)alloc((size_t)KK * 2048 * 2);
    __hip_bfloat16* w1T   = (__hip_bfloat16*)alloc((size_t)1024 * KK * 2);
    __hip_bfloat16* w2T   = (__hip_bfloat16*)alloc((size_t)KK * 1024 * 2);
    __hip_bfloat16* qk    = (__hip_bfloat16*)alloc((size_t)MM * QKS * 2);
    __hip_bfloat16* vt    = (__hip_bfloat16*)alloc((size_t)32 * KK * TT * 2);
    __hip_bfloat16* attn  = (__hip_bfloat16*)alloc((size_t)MM * 2048 * 2);
    float*          y1    = (float*)alloc((size_t)MM * KK * 4);
    float*          x1    = (float*)alloc((size_t)MM * KK * 4);
    __hip_bfloat16* x1b   = (__hip_bfloat16*)alloc((size_t)MM * KK * 2);
    __hip_bfloat16* hid   = (__hip_bfloat16*)alloc((size_t)MM * 1024 * 2);
    float*          y2    = (float*)alloc((size_t)MM * KK * 4);

    // 1. fused prep (cvt + 6 transposes)
    prep_k<<<4608, 256, 0, stream>>>(x, xb, wq, wk, wv, wu, w1, w2,
                                     wqkvT, wuT, w1T, w2T);

    // 2. QKV projection; q/k scale 0.25*sqrt(log2 e); V fused-transposed into vt
    gemm_k<0, 128, 128><<<dim3(NQKV / 128, MM / 128), 256, 0, stream>>>(
        xb, wqkvT, MM, NQKV, 256, nullptr, nullptr, qk, 0.3002806f, vt);

    // 3. flash attention
    attn_k<<<dim3(256), 512, 0, stream>>>(qk, vt, attn);

    // 4. attn-out proj + residual -> y1 (f32); LN1 -> x1 + x1b   (BM=32: 1024 blocks)
    gemm_k<1, 64, 32><<<dim3(4, MM / 32), 256, 0, stream>>>(
        attn, wuT, MM, 256, 2048, bu, x, y1, 1.0f, nullptr);
    layernorm_k<<<MM / 4, 256, 0, stream>>>(y1, g1, be1, x1, x1b);

    // 5. FFN1: relu(x1b @ w1 + b1) -> hid (bf16)
    gemm_k<2, 128, 128><<<dim3(8, MM / 128), 256, 0, stream>>>(
        x1b, w1T, MM, 1024, 256, b1, nullptr, hid, 1.0f, nullptr);

    // 6. FFN2 + residual -> y2; LN2 -> d_out   (BM=32: 1024 blocks)
    gemm_k<1, 64, 32><<<dim3(4, MM / 32), 256, 0, stream>>>(
        hid, w2T, MM, 256, 1024, b2, x1, y2, 1.0f, nullptr);
    layernorm_k<<<MM / 4, 256, 0, stream>>>(y2, g2, be2, (float*)d_out, nullptr);
}